// Round 1
// baseline (1954.753 us; speedup 1.0000x reference)
//
#include <hip/hip_runtime.h>
#include <math.h>

#define EPSV 1e-5f

// ---------------------------------------------------------------------------
// Kernel 1: fused conv1(1->32,3x3,pad1)+relu+pool2  then conv2(32->64)+relu+pool2
// One block per image (N=4096 blocks, 256 threads).
// Output: feat (N, 3136) with flatten order oc*49 + py*7 + px  == reshape(N,-1)
// ---------------------------------------------------------------------------
__global__ __launch_bounds__(256) void conv_fused(
    const float* __restrict__ x,     // (N,1,28,28)
    const float* __restrict__ w1,    // (32,1,3,3)
    const float* __restrict__ b1,    // (32,)
    const float* __restrict__ w2,    // (64,32,3,3)
    const float* __restrict__ b2,    // (64,)
    float* __restrict__ feat)        // (N,3136)
{
    __shared__ float in_pad[30 * 30];      // zero-padded input
    __shared__ float w1s[288];
    __shared__ float b1s[32];
    __shared__ float buf1[32][16 * 18];    // conv1 pooled output, padded: rows 16, stride 18

    const int tid = threadIdx.x;
    const int n = blockIdx.x;

    // Phase A: zero LDS, load conv1 weights
    for (int i = tid; i < 900; i += 256) in_pad[i] = 0.f;
    for (int i = tid; i < 32 * 288; i += 256) ((float*)buf1)[i] = 0.f;
    for (int i = tid; i < 288; i += 256) w1s[i] = w1[i];
    if (tid < 32) b1s[tid] = b1[tid];
    __syncthreads();

    // Phase B: stage input interior
    const float* xin = x + (size_t)n * 784;
    for (int i = tid; i < 784; i += 256) {
        int yy = i / 28, xx = i - yy * 28;
        in_pad[(yy + 1) * 30 + (xx + 1)] = xin[i];
    }
    __syncthreads();

    // Phase C: conv1 + relu + maxpool2 -> buf1 (32 x 14 x 14 at padded coords +1)
    for (int idx = tid; idx < 6272; idx += 256) {
        int oc = idx / 196;
        int p = idx - oc * 196;
        int py = p / 14, px = p - py * 14;
        float patch[4][4];
        #pragma unroll
        for (int r = 0; r < 4; ++r)
            #pragma unroll
            for (int cc = 0; cc < 4; ++cc)
                patch[r][cc] = in_pad[(2 * py + r) * 30 + (2 * px + cc)];
        float wv[9];
        #pragma unroll
        for (int j = 0; j < 9; ++j) wv[j] = w1s[oc * 9 + j];
        float bias = b1s[oc];
        float m = 0.f;   // relu then max == max(0, convs)
        #pragma unroll
        for (int dy2 = 0; dy2 < 2; ++dy2)
            #pragma unroll
            for (int dx2 = 0; dx2 < 2; ++dx2) {
                float s = bias;
                #pragma unroll
                for (int dy = 0; dy < 3; ++dy)
                    #pragma unroll
                    for (int dx = 0; dx < 3; ++dx)
                        s += patch[dy2 + dy][dx2 + dx] * wv[dy * 3 + dx];
                m = fmaxf(m, s);
            }
        buf1[oc][(py + 1) * 18 + (px + 1)] = m;
    }
    __syncthreads();

    // Phase D: conv2 + relu + maxpool2 -> feat row
    float* fo = feat + (size_t)n * 3136;
    for (int idx = tid; idx < 3136; idx += 256) {
        int oc = idx / 49;
        int p = idx - oc * 49;
        int py = p / 7, px = p - py * 7;
        float bias = b2[oc];
        float a00 = bias, a01 = bias, a10 = bias, a11 = bias;
        const float* wp = w2 + oc * 288;
        for (int ic = 0; ic < 32; ++ic) {
            float patch[4][4];
            #pragma unroll
            for (int r = 0; r < 4; ++r)
                #pragma unroll
                for (int cc = 0; cc < 4; ++cc)
                    patch[r][cc] = buf1[ic][(2 * py + r) * 18 + (2 * px + cc)];
            float wv[9];
            #pragma unroll
            for (int j = 0; j < 9; ++j) wv[j] = wp[ic * 9 + j];
            #pragma unroll
            for (int dy = 0; dy < 3; ++dy)
                #pragma unroll
                for (int dx = 0; dx < 3; ++dx) {
                    float w = wv[dy * 3 + dx];
                    a00 += patch[dy    ][dx    ] * w;
                    a01 += patch[dy    ][dx + 1] * w;
                    a10 += patch[dy + 1][dx    ] * w;
                    a11 += patch[dy + 1][dx + 1] * w;
                }
        }
        float m = fmaxf(fmaxf(a00, a01), fmaxf(a10, a11));
        fo[idx] = fmaxf(m, 0.f);
    }
}

// ---------------------------------------------------------------------------
// Kernel 2: FC  h[n][d] = feat[n] . fc_w[d] + fc_b[d]     (N=4096, D=32, K=3136)
// ---------------------------------------------------------------------------
__global__ __launch_bounds__(256) void fc_kernel(
    const float* __restrict__ feat,  // (N,3136)
    const float* __restrict__ fw,    // (32,3136)
    const float* __restrict__ fb,    // (32,)
    float* __restrict__ h)           // (N,32)
{
    int gid = blockIdx.x * 256 + threadIdx.x;   // n*32 + d, 512 blocks exact
    int d = gid & 31;
    int n = gid >> 5;
    const float4* fr = (const float4*)(feat + (size_t)n * 3136);
    const float4* wr = (const float4*)(fw + (size_t)d * 3136);
    float acc = 0.f;
    for (int k = 0; k < 784; ++k) {
        float4 a = fr[k];
        float4 b = wr[k];
        acc += a.x * b.x + a.y * b.y + a.z * b.z + a.w * b.w;
    }
    h[gid] = acc + fb[d];
}

// ---------------------------------------------------------------------------
// Kernel 3: hyperbolic MLR head. One thread per (n,k). c = 1.
// ---------------------------------------------------------------------------
__global__ __launch_bounds__(256) void mlr_kernel(
    const float* __restrict__ h,    // (N,32)
    const float* __restrict__ hw,   // (10,32)
    const float* __restrict__ hb,   // (10,32)
    float* __restrict__ out)        // (N,10)
{
    int gid = blockIdx.x * 256 + threadIdx.x;
    if (gid >= 4096 * 10) return;
    int n = gid / 10;
    int k = gid - n * 10;
    const float* xr = h + n * 32;
    const float* wr = hw + k * 32;
    const float* br = hb + k * 32;

    float x2 = 0.f, b2 = 0.f, ww = 0.f, xb = 0.f, xw = 0.f, wb = 0.f;
    #pragma unroll
    for (int i = 0; i < 32; ++i) {
        float xi = xr[i], wi = wr[i], bi = br[i];
        x2 += xi * xi;
        b2 += bi * bi;
        ww += wi * wi;
        xb += xi * bi;
        xw += xi * wi;
        wb += wi * bi;
    }
    float w_norm = sqrtf(ww);
    float wnc = fmaxf(w_norm, 1e-12f);
    float inner = -xb;                       // x . (-b)
    float a_num = 1.f + 2.f * inner + x2;
    float b_num = 1.f - b2;
    float den = 1.f + 2.f * inner + x2 * b2;
    float alpha = a_num / fmaxf(den, EPSV);
    float beta = b_num / den;                // raw denom, as in source
    float mob2 = alpha * alpha * b2 + 2.f * alpha * beta * inner + beta * beta * x2;
    float sq = sqrtf(mob2);
    const float MAXN = (float)(1.0 - 1e-5);
    const float MAXN2 = (float)((1.0 - 1e-5) * (1.0 - 1e-5));
    float normalizer = (sq > MAXN) ? (MAXN / fmaxf(sq, EPSV)) : 1.f;
    float mob2c = (sq < MAXN) ? mob2 : MAXN2;
    float hyper = (alpha * (-wb) + beta * xw) / wnc;  // alpha*sum(wn*-b) + beta*(x.wn)
    hyper *= normalizer;
    float asin_in = 2.f * hyper / fmaxf(1.f - mob2c, EPSV);
    float scaler = 2.f / fmaxf(1.f - b2, EPSV);
    out[gid] = scaler * w_norm * asinhf(asin_in);
}

// ---------------------------------------------------------------------------
extern "C" void kernel_launch(void* const* d_in, const int* in_sizes, int n_in,
                              void* d_out, int out_size, void* d_ws, size_t ws_size,
                              hipStream_t stream) {
    const float* x   = (const float*)d_in[0];
    const float* w1  = (const float*)d_in[1];
    const float* b1  = (const float*)d_in[2];
    const float* w2  = (const float*)d_in[3];
    const float* b2  = (const float*)d_in[4];
    const float* fw  = (const float*)d_in[5];
    const float* fb  = (const float*)d_in[6];
    const float* hw  = (const float*)d_in[7];
    const float* hb  = (const float*)d_in[8];
    float* out = (float*)d_out;

    const int N = 4096;
    float* feat = (float*)d_ws;                       // N*3136 floats
    float* h    = feat + (size_t)N * 3136;            // N*32 floats

    conv_fused<<<N, 256, 0, stream>>>(x, w1, b1, w2, b2, feat);
    fc_kernel<<<(N * 32) / 256, 256, 0, stream>>>(feat, fw, fb, h);
    mlr_kernel<<<(N * 10 + 255) / 256, 256, 0, stream>>>(h, hw, hb, out);
}

// Round 2
// 437.145 us; speedup vs baseline: 4.4716x; 4.4716x over previous
//
#include <hip/hip_runtime.h>
#include <math.h>

#define EPSV 1e-5f

// ---------------------------------------------------------------------------
// Kernel 1: fused conv1(1->32,3x3,pad1)+relu+pool2 then conv2(32->64)+relu+pool2
// One block per image (N=4096 blocks, 256 threads = 4 waves).
// Phase C: wave w owns oc group [8w, 8w+8); lane owns a pooled position.
// Phase D: wave w owns oc group [16w, 16w+16); lane owns one of 49 pooled pos.
// Weights are read with wave-uniform indices -> scalar loads (s_load), used as
// the SGPR operand of v_fmac_f32. Patches read once per (pos,ic) via float2.
// Output: feat (N, 3136), flatten order oc*49 + py*7 + px == reshape(N,-1).
// ---------------------------------------------------------------------------
__global__ __launch_bounds__(256) void conv_fused(
    const float* __restrict__ x,     // (N,1,28,28)
    const float* __restrict__ w1,    // (32,1,3,3)
    const float* __restrict__ b1,    // (32,)
    const float* __restrict__ w2,    // (64,32,3,3)
    const float* __restrict__ b2,    // (64,)
    float* __restrict__ feat)        // (N,3136)
{
    __shared__ float in_pad[30 * 30];      // zero-padded 28x28 input
    __shared__ float buf1[32][16 * 18];    // conv1 pooled (14x14) padded to 16 rows, stride 18

    const int tid  = threadIdx.x;
    const int lane = tid & 63;
    const int wave = tid >> 6;
    const int n    = blockIdx.x;

    // Phase A: zero pad borders / buffers
    for (int i = tid; i < 900; i += 256) in_pad[i] = 0.f;
    for (int i = tid; i < 32 * 288; i += 256) ((float*)buf1)[i] = 0.f;
    __syncthreads();

    // Phase B: stage input interior
    const float* xin = x + (size_t)n * 784;
    for (int i = tid; i < 784; i += 256) {
        int yy = i / 28, xx = i - yy * 28;
        in_pad[(yy + 1) * 30 + (xx + 1)] = xin[i];
    }
    __syncthreads();

    // Phase C: conv1 + relu + maxpool2 -> buf1 interior (rows/cols +1)
    {
        const int ocb = __builtin_amdgcn_readfirstlane(wave * 8);
        for (int r = 0; r < 4; ++r) {
            int pos = r * 64 + lane;                  // 0..195 valid
            bool valid = pos < 196;
            int posc = valid ? pos : 195;
            int py = posc / 14, px = posc - py * 14;
            float p[4][4];
            #pragma unroll
            for (int rr = 0; rr < 4; ++rr) {
                const float2* rp = (const float2*)&in_pad[(2 * py + rr) * 30 + 2 * px];
                float2 a = rp[0], b = rp[1];
                p[rr][0] = a.x; p[rr][1] = a.y; p[rr][2] = b.x; p[rr][3] = b.y;
            }
            #pragma unroll
            for (int o = 0; o < 8; ++o) {
                const float* wv = w1 + (ocb + o) * 9;    // wave-uniform -> s_load
                float bias = b1[ocb + o];
                float m = 0.f;                            // relu(max) == max(0,...)
                #pragma unroll
                for (int q = 0; q < 4; ++q) {
                    int dy = q >> 1, dx = q & 1;
                    float s = bias;
                    #pragma unroll
                    for (int ky = 0; ky < 3; ++ky)
                        #pragma unroll
                        for (int kx = 0; kx < 3; ++kx)
                            s += p[dy + ky][dx + kx] * wv[ky * 3 + kx];
                    m = fmaxf(m, s);
                }
                if (valid) buf1[ocb + o][(py + 1) * 18 + (px + 1)] = m;
            }
        }
    }
    __syncthreads();

    // Phase D: conv2 + relu + maxpool2 -> feat row
    {
        const int ocb = __builtin_amdgcn_readfirstlane(wave * 16);
        const int posc = (lane < 49) ? lane : 48;       // clamp: no divergence in body
        const int py = posc / 7, px = posc - py * 7;

        float acc[16][4];
        #pragma unroll
        for (int o = 0; o < 16; ++o) {
            float bias = b2[ocb + o];                   // uniform -> s_load
            acc[o][0] = bias; acc[o][1] = bias; acc[o][2] = bias; acc[o][3] = bias;
        }

        for (int ic = 0; ic < 32; ++ic) {
            float p[4][4];
            #pragma unroll
            for (int rr = 0; rr < 4; ++rr) {
                const float2* rp = (const float2*)&buf1[ic][(2 * py + rr) * 18 + 2 * px];
                float2 a = rp[0], b = rp[1];
                p[rr][0] = a.x; p[rr][1] = a.y; p[rr][2] = b.x; p[rr][3] = b.y;
            }
            const float* wb = w2 + (size_t)ocb * 288 + ic * 9;   // wave-uniform base
            #pragma unroll
            for (int o = 0; o < 16; ++o) {
                const float* wv = wb + o * 288;                  // uniform -> s_load
                #pragma unroll
                for (int ky = 0; ky < 3; ++ky)
                    #pragma unroll
                    for (int kx = 0; kx < 3; ++kx) {
                        float w = wv[ky * 3 + kx];
                        acc[o][0] += p[ky    ][kx    ] * w;
                        acc[o][1] += p[ky    ][kx + 1] * w;
                        acc[o][2] += p[ky + 1][kx    ] * w;
                        acc[o][3] += p[ky + 1][kx + 1] * w;
                    }
            }
        }

        if (lane < 49) {
            float* fo = feat + (size_t)n * 3136;
            #pragma unroll
            for (int o = 0; o < 16; ++o) {
                float m = fmaxf(fmaxf(acc[o][0], acc[o][1]), fmaxf(acc[o][2], acc[o][3]));
                fo[(ocb + o) * 49 + posc] = fmaxf(m, 0.f);
            }
        }
    }
}

// ---------------------------------------------------------------------------
// Kernel 2: FC as tiled GEMM. Block = 16 images x all 32 outputs.
// LDS stage feat[16][224] + fw[32][224] per chunk (stride padded to 228).
// ---------------------------------------------------------------------------
__global__ __launch_bounds__(256) void fc_kernel(
    const float* __restrict__ feat,  // (N,3136)
    const float* __restrict__ fw,    // (32,3136)
    const float* __restrict__ fb,    // (32,)
    float* __restrict__ h)           // (N,32)
{
    __shared__ float fs[16][228];
    __shared__ float ws[32][228];
    const int tid = threadIdx.x;
    const int n0 = blockIdx.x * 16;
    const int nn = tid >> 4;         // 0..15
    const int dd = tid & 15;         // 0..15 -> outputs dd and dd+16
    float acc0 = 0.f, acc1 = 0.f;

    for (int c = 0; c < 14; ++c) {
        __syncthreads();
        for (int i = tid; i < 896; i += 256) {          // feat: 16 rows x 56 float4
            int row = i / 56, col = i - row * 56;
            float4 v = *(const float4*)&feat[(size_t)(n0 + row) * 3136 + c * 224 + col * 4];
            *(float4*)&fs[row][col * 4] = v;
        }
        for (int i = tid; i < 1792; i += 256) {         // fw: 32 rows x 56 float4
            int row = i / 56, col = i - row * 56;
            float4 v = *(const float4*)&fw[(size_t)row * 3136 + c * 224 + col * 4];
            *(float4*)&ws[row][col * 4] = v;
        }
        __syncthreads();
        #pragma unroll 8
        for (int k = 0; k < 56; ++k) {
            float4 a  = *(const float4*)&fs[nn][k * 4];
            float4 b0 = *(const float4*)&ws[dd][k * 4];
            float4 b1 = *(const float4*)&ws[dd + 16][k * 4];
            acc0 += a.x * b0.x + a.y * b0.y + a.z * b0.z + a.w * b0.w;
            acc1 += a.x * b1.x + a.y * b1.y + a.z * b1.z + a.w * b1.w;
        }
    }
    h[(size_t)(n0 + nn) * 32 + dd]      = acc0 + fb[dd];
    h[(size_t)(n0 + nn) * 32 + dd + 16] = acc1 + fb[dd + 16];
}

// ---------------------------------------------------------------------------
// Kernel 3: hyperbolic MLR head. One thread per (n,k). c = 1.
// ---------------------------------------------------------------------------
__global__ __launch_bounds__(256) void mlr_kernel(
    const float* __restrict__ h,    // (N,32)
    const float* __restrict__ hw,   // (10,32)
    const float* __restrict__ hb,   // (10,32)
    float* __restrict__ out)        // (N,10)
{
    int gid = blockIdx.x * 256 + threadIdx.x;
    if (gid >= 4096 * 10) return;
    int n = gid / 10;
    int k = gid - n * 10;
    const float* xr = h + n * 32;
    const float* wr = hw + k * 32;
    const float* br = hb + k * 32;

    float x2 = 0.f, b2 = 0.f, ww = 0.f, xb = 0.f, xw = 0.f, wb = 0.f;
    #pragma unroll
    for (int i = 0; i < 32; ++i) {
        float xi = xr[i], wi = wr[i], bi = br[i];
        x2 += xi * xi;
        b2 += bi * bi;
        ww += wi * wi;
        xb += xi * bi;
        xw += xi * wi;
        wb += wi * bi;
    }
    float w_norm = sqrtf(ww);
    float wnc = fmaxf(w_norm, 1e-12f);
    float inner = -xb;                       // x . (-b)
    float a_num = 1.f + 2.f * inner + x2;
    float b_num = 1.f - b2;
    float den = 1.f + 2.f * inner + x2 * b2;
    float alpha = a_num / fmaxf(den, EPSV);
    float beta = b_num / den;                // raw denom, as in source
    float mob2 = alpha * alpha * b2 + 2.f * alpha * beta * inner + beta * beta * x2;
    float sq = sqrtf(mob2);
    const float MAXN = (float)(1.0 - 1e-5);
    const float MAXN2 = (float)((1.0 - 1e-5) * (1.0 - 1e-5));
    float normalizer = (sq > MAXN) ? (MAXN / fmaxf(sq, EPSV)) : 1.f;
    float mob2c = (sq < MAXN) ? mob2 : MAXN2;
    float hyper = (alpha * (-wb) + beta * xw) / wnc;  // alpha*sum(wn*-b) + beta*(x.wn)
    hyper *= normalizer;
    float asin_in = 2.f * hyper / fmaxf(1.f - mob2c, EPSV);
    float scaler = 2.f / fmaxf(1.f - b2, EPSV);
    out[gid] = scaler * w_norm * asinhf(asin_in);
}

// ---------------------------------------------------------------------------
extern "C" void kernel_launch(void* const* d_in, const int* in_sizes, int n_in,
                              void* d_out, int out_size, void* d_ws, size_t ws_size,
                              hipStream_t stream) {
    const float* x   = (const float*)d_in[0];
    const float* w1  = (const float*)d_in[1];
    const float* b1  = (const float*)d_in[2];
    const float* w2  = (const float*)d_in[3];
    const float* b2  = (const float*)d_in[4];
    const float* fw  = (const float*)d_in[5];
    const float* fb  = (const float*)d_in[6];
    const float* hw  = (const float*)d_in[7];
    const float* hb  = (const float*)d_in[8];
    float* out = (float*)d_out;

    const int N = 4096;
    float* feat = (float*)d_ws;                       // N*3136 floats
    float* h    = feat + (size_t)N * 3136;            // N*32 floats

    conv_fused<<<N, 256, 0, stream>>>(x, w1, b1, w2, b2, feat);
    fc_kernel<<<N / 16, 256, 0, stream>>>(feat, fw, fb, h);
    mlr_kernel<<<(N * 10 + 255) / 256, 256, 0, stream>>>(h, hw, hb, out);
}

// Round 4
// 272.999 us; speedup vs baseline: 7.1603x; 1.6013x over previous
//
#include <hip/hip_runtime.h>
#include <math.h>

#define EPSV 1e-5f

typedef _Float16 f16x8 __attribute__((ext_vector_type(8)));
typedef float f32x4 __attribute__((ext_vector_type(4)));

// ---------------------------------------------------------------------------
// Kernel 0: weight prep -> split-fp16 (hi,lo) pairs.
// w2t[off][oc][ic] (9,64,32) from w2 (64,32,3,3); fw (32,3136) row-major.
// ---------------------------------------------------------------------------
__global__ __launch_bounds__(256) void prep_weights(
    const float* __restrict__ w2, const float* __restrict__ fw,
    _Float16* __restrict__ w2t_hi, _Float16* __restrict__ w2t_lo,
    _Float16* __restrict__ fw_hi,  _Float16* __restrict__ fw_lo)
{
    int idx = blockIdx.x * 256 + threadIdx.x;
    if (idx < 18432) {
        int off = idx >> 11;            // /2048 (9*2048=18432)
        int rem = idx & 2047;
        int oc = rem >> 5, ic = rem & 31;
        float v = w2[(oc * 32 + ic) * 9 + off];
        _Float16 hx = (_Float16)v;
        w2t_hi[idx] = hx;
        w2t_lo[idx] = (_Float16)(v - (float)hx);
    } else if (idx < 18432 + 100352) {
        int j = idx - 18432;
        float v = fw[j];
        _Float16 hx = (_Float16)v;
        fw_hi[j] = hx;
        fw_lo[j] = (_Float16)(v - (float)hx);
    }
}

// ---------------------------------------------------------------------------
// Kernel 1: conv1(1->32)+relu+pool (fp32 VALU, split to hi/lo LDS) ->
//           conv2(32->64) via split-fp16 MFMA (3 MFMA per tap: hh+lh+hl) ->
//           2x2 pool IN REGISTERS (shfl_xor + adjacent acc rows) ->
//           feat hi/lo fp16 planes.
// One block per image, 256 threads = 4 waves. Row-aligned N-tiles: tile = one
// 14-wide conv2 output row (lanes cl=0..13 used, 14,15 dead).
// LDS: in_pad[900]f32 | Bbuf_hi[4][16][16][8]f16 | Bbuf_lo[...] (+pad).
// ---------------------------------------------------------------------------
__global__ __launch_bounds__(256) void conv_fused(
    const float* __restrict__ x,       // (N,1,28,28)
    const float* __restrict__ w1,      // (32,1,3,3)
    const float* __restrict__ b1,      // (32,)
    const _Float16* __restrict__ w2t_hi, // (9,64,32)
    const _Float16* __restrict__ w2t_lo,
    const float* __restrict__ b2,      // (64,)
    _Float16* __restrict__ feat_hi,    // (N,3136)
    _Float16* __restrict__ feat_lo)    // (N,3136)
{
    __shared__ float4 smem4[2280];                       // 36480 B
    float*    in_pad  = (float*)smem4;                   // [900]   @0
    _Float16* Bbuf_hi = (_Float16*)((char*)smem4 + 3600);  // 16384 B
    _Float16* Bbuf_lo = (_Float16*)((char*)smem4 + 19984); // 16384 B (+pad 112)

    const int tid  = threadIdx.x;
    const int lane = tid & 63;
    const int wave = tid >> 6;
    const int kg   = lane >> 4;      // 0..3
    const int cl   = lane & 15;      // 0..15
    const int n    = blockIdx.x;

    // Phase A: zero in_pad + Bbuf_hi + Bbuf_lo (+pad) = 9120 dwords
    for (int i = tid; i < 9120; i += 256) ((int*)smem4)[i] = 0;
    __syncthreads();

    // Phase B: stage input interior
    const float* xin = x + (size_t)n * 784;
    for (int i = tid; i < 784; i += 256) {
        int yy = i / 28, xx = i - yy * 28;
        in_pad[(yy + 1) * 30 + (xx + 1)] = xin[i];
    }
    __syncthreads();

    // Phase C: conv1 + relu + pool -> Bbuf hi/lo (wave = ic-group, 8 ics/lane-pos)
    {
        const int icb = __builtin_amdgcn_readfirstlane(wave * 8);
        for (int r = 0; r < 4; ++r) {
            int pos = r * 64 + lane;                  // 0..195 valid
            bool valid = pos < 196;
            int posc = valid ? pos : 195;
            int py = posc / 14, px = posc - py * 14;
            float p[4][4];
            #pragma unroll
            for (int rr = 0; rr < 4; ++rr) {
                const float2* rp = (const float2*)&in_pad[(2 * py + rr) * 30 + 2 * px];
                float2 a = rp[0], b = rp[1];
                p[rr][0] = a.x; p[rr][1] = a.y; p[rr][2] = b.x; p[rr][3] = b.y;
            }
            f16x8 vhi, vlo;
            #pragma unroll
            for (int o = 0; o < 8; ++o) {
                const float* wv = w1 + (icb + o) * 9;    // wave-uniform -> s_load
                float bias = b1[icb + o];
                float m = 0.f;
                #pragma unroll
                for (int q = 0; q < 4; ++q) {
                    int dy = q >> 1, dx = q & 1;
                    float s = bias;
                    #pragma unroll
                    for (int ky = 0; ky < 3; ++ky)
                        #pragma unroll
                        for (int kx = 0; kx < 3; ++kx)
                            s += p[dy + ky][dx + kx] * wv[ky * 3 + kx];
                    m = fmaxf(m, s);
                }
                _Float16 hx = (_Float16)m;
                vhi[o] = hx;
                vlo[o] = (_Float16)(m - (float)hx);
            }
            if (valid) {
                int cell = (wave * 256 + (py + 1) * 16 + (px + 1)) * 8;
                *(f16x8*)(Bbuf_hi + cell) = vhi;
                *(f16x8*)(Bbuf_lo + cell) = vlo;
            }
        }
    }
    __syncthreads();

    // Phase D: conv2 via split-fp16 MFMA. Wave owns 16 ocs; tile = output row.
    const int ocb = wave * 16;
    float bias[4];
    #pragma unroll
    for (int r = 0; r < 4; ++r) bias[r] = b2[ocb + kg * 4 + r];

    f32x4 acc[14];
    #pragma unroll
    for (int t = 0; t < 14; ++t) acc[t] = (f32x4){0.f, 0.f, 0.f, 0.f};

    #pragma unroll
    for (int off = 0; off < 9; ++off) {
        const int ky = off / 3, kx = off - ky * 3;
        f16x8 a_hi = *(const f16x8*)(w2t_hi + ((size_t)off * 64 + ocb + cl) * 32 + kg * 8);
        f16x8 a_lo = *(const f16x8*)(w2t_lo + ((size_t)off * 64 + ocb + cl) * 32 + kg * 8);
        const int base = (kg * 256 + ky * 16 + (cl + kx)) * 8;   // + py*128 per row
        #pragma unroll
        for (int py = 0; py < 14; ++py) {
            f16x8 b_hi = *(const f16x8*)(Bbuf_hi + base + py * 128);
            f16x8 b_lo = *(const f16x8*)(Bbuf_lo + base + py * 128);
            acc[py] = __builtin_amdgcn_mfma_f32_16x16x32_f16(a_hi, b_hi, acc[py], 0, 0, 0);
            acc[py] = __builtin_amdgcn_mfma_f32_16x16x32_f16(a_lo, b_hi, acc[py], 0, 0, 0);
            acc[py] = __builtin_amdgcn_mfma_f32_16x16x32_f16(a_hi, b_lo, acc[py], 0, 0, 0);
        }
    }
    __syncthreads();   // Bbuf dead; Fbuf may alias

    // Pool in registers: D layout col=cl (x pos), row regs = oc kg*4+r.
    // Horizontal pool partner = lane cl^1; vertical = adjacent acc row.
    _Float16* Fhi = (_Float16*)smem4;          // 3136 fp16 = 6272 B
    _Float16* Flo = Fhi + 3136;                // next 6272 B
    const bool wlane = ((cl & 1) == 0) && (cl < 14);
    const int px2 = cl >> 1;
    #pragma unroll
    for (int p2 = 0; p2 < 7; ++p2) {
        f32x4 r0 = acc[2 * p2], r1 = acc[2 * p2 + 1];
        #pragma unroll
        for (int r = 0; r < 4; ++r) {
            float v0 = fmaxf(r0[r], __shfl_xor(r0[r], 1));
            float v1 = fmaxf(r1[r], __shfl_xor(r1[r], 1));
            float m = fmaxf(fmaxf(v0, v1) + bias[r], 0.f);
            _Float16 mh = (_Float16)m;
            _Float16 ml = (_Float16)(m - (float)mh);
            if (wlane) {
                int o = (ocb + kg * 4 + r) * 49 + p2 * 7 + px2;
                Fhi[o] = mh;
                Flo[o] = ml;
            }
        }
    }
    __syncthreads();

    // Coalesced dump: 1568 dwords per plane
    unsigned* gh = (unsigned*)(feat_hi + (size_t)n * 3136);
    unsigned* gl = (unsigned*)(feat_lo + (size_t)n * 3136);
    const unsigned* sh = (const unsigned*)Fhi;
    const unsigned* sl = (const unsigned*)Flo;
    for (int i = tid; i < 1568; i += 256) { gh[i] = sh[i]; gl[i] = sl[i]; }
}

// ---------------------------------------------------------------------------
// Kernel 2: FC via split-fp16 MFMA. M=4096, N=32, K=3136. One wave per block,
// 256 blocks; wave = 16-image M-tile x both 16-col N-tiles. 6 MFMA per k-step.
// ---------------------------------------------------------------------------
__global__ __launch_bounds__(64) void fc_mfma(
    const _Float16* __restrict__ feat_hi, const _Float16* __restrict__ feat_lo,
    const _Float16* __restrict__ fw_hi,   const _Float16* __restrict__ fw_lo,
    const float* __restrict__ fb,         float* __restrict__ h)
{
    const int lane = threadIdx.x;
    const int kg = lane >> 4, cl = lane & 15;
    const int m0 = blockIdx.x * 16;

    const _Float16* ah  = feat_hi + (size_t)(m0 + cl) * 3136 + kg * 8;
    const _Float16* al  = feat_lo + (size_t)(m0 + cl) * 3136 + kg * 8;
    const _Float16* b0h = fw_hi + (size_t)cl * 3136 + kg * 8;
    const _Float16* b0l = fw_lo + (size_t)cl * 3136 + kg * 8;
    const _Float16* b1h = fw_hi + (size_t)(16 + cl) * 3136 + kg * 8;
    const _Float16* b1l = fw_lo + (size_t)(16 + cl) * 3136 + kg * 8;

    f32x4 acc0 = {0.f, 0.f, 0.f, 0.f}, acc1 = {0.f, 0.f, 0.f, 0.f};
    for (int k0 = 0; k0 < 3136; k0 += 32) {
        f16x8 vah = *(const f16x8*)(ah + k0);
        f16x8 val_ = *(const f16x8*)(al + k0);
        f16x8 v0h = *(const f16x8*)(b0h + k0);
        f16x8 v0l = *(const f16x8*)(b0l + k0);
        f16x8 v1h = *(const f16x8*)(b1h + k0);
        f16x8 v1l = *(const f16x8*)(b1l + k0);
        acc0 = __builtin_amdgcn_mfma_f32_16x16x32_f16(vah, v0h, acc0, 0, 0, 0);
        acc0 = __builtin_amdgcn_mfma_f32_16x16x32_f16(val_, v0h, acc0, 0, 0, 0);
        acc0 = __builtin_amdgcn_mfma_f32_16x16x32_f16(vah, v0l, acc0, 0, 0, 0);
        acc1 = __builtin_amdgcn_mfma_f32_16x16x32_f16(vah, v1h, acc1, 0, 0, 0);
        acc1 = __builtin_amdgcn_mfma_f32_16x16x32_f16(val_, v1h, acc1, 0, 0, 0);
        acc1 = __builtin_amdgcn_mfma_f32_16x16x32_f16(vah, v1l, acc1, 0, 0, 0);
    }
    float fb0 = fb[cl], fb1 = fb[16 + cl];
    #pragma unroll
    for (int r = 0; r < 4; ++r) {
        int im = m0 + kg * 4 + r;
        h[(size_t)im * 32 + cl]      = acc0[r] + fb0;
        h[(size_t)im * 32 + 16 + cl] = acc1[r] + fb1;
    }
}

// ---------------------------------------------------------------------------
// Kernel 3: hyperbolic MLR head (fp32). One thread per (n,k). c = 1.
// ---------------------------------------------------------------------------
__global__ __launch_bounds__(256) void mlr_kernel(
    const float* __restrict__ h,    // (N,32)
    const float* __restrict__ hw,   // (10,32)
    const float* __restrict__ hb,   // (10,32)
    float* __restrict__ out)        // (N,10)
{
    int gid = blockIdx.x * 256 + threadIdx.x;
    if (gid >= 4096 * 10) return;
    int n = gid / 10;
    int k = gid - n * 10;
    const float* xr = h + n * 32;
    const float* wr = hw + k * 32;
    const float* br = hb + k * 32;

    float x2 = 0.f, b2 = 0.f, ww = 0.f, xb = 0.f, xw = 0.f, wb = 0.f;
    #pragma unroll
    for (int i = 0; i < 32; ++i) {
        float xi = xr[i], wi = wr[i], bi = br[i];
        x2 += xi * xi;
        b2 += bi * bi;
        ww += wi * wi;
        xb += xi * bi;
        xw += xi * wi;
        wb += wi * bi;
    }
    float w_norm = sqrtf(ww);
    float wnc = fmaxf(w_norm, 1e-12f);
    float inner = -xb;                       // x . (-b)
    float a_num = 1.f + 2.f * inner + x2;
    float b_num = 1.f - b2;
    float den = 1.f + 2.f * inner + x2 * b2;
    float alpha = a_num / fmaxf(den, EPSV);
    float beta = b_num / den;                // raw denom, as in source
    float mob2 = alpha * alpha * b2 + 2.f * alpha * beta * inner + beta * beta * x2;
    float sq = sqrtf(mob2);
    const float MAXN = (float)(1.0 - 1e-5);
    const float MAXN2 = (float)((1.0 - 1e-5) * (1.0 - 1e-5));
    float normalizer = (sq > MAXN) ? (MAXN / fmaxf(sq, EPSV)) : 1.f;
    float mob2c = (sq < MAXN) ? mob2 : MAXN2;
    float hyper = (alpha * (-wb) + beta * xw) / wnc;
    hyper *= normalizer;
    float asin_in = 2.f * hyper / fmaxf(1.f - mob2c, EPSV);
    float scaler = 2.f / fmaxf(1.f - b2, EPSV);
    out[gid] = scaler * w_norm * asinhf(asin_in);
}

// ---------------------------------------------------------------------------
extern "C" void kernel_launch(void* const* d_in, const int* in_sizes, int n_in,
                              void* d_out, int out_size, void* d_ws, size_t ws_size,
                              hipStream_t stream) {
    const float* x   = (const float*)d_in[0];
    const float* w1  = (const float*)d_in[1];
    const float* b1  = (const float*)d_in[2];
    const float* w2  = (const float*)d_in[3];
    const float* b2  = (const float*)d_in[4];
    const float* fw  = (const float*)d_in[5];
    const float* fb  = (const float*)d_in[6];
    const float* hw  = (const float*)d_in[7];
    const float* hb  = (const float*)d_in[8];
    float* out = (float*)d_out;

    const int N = 4096;
    char* ws = (char*)d_ws;
    _Float16* feat_hi = (_Float16*)ws;                        // 25,690,112 B
    _Float16* feat_lo = (_Float16*)(ws + 25690112);           // 25,690,112 B
    float*    h       = (float*)(ws + 51380224);              //    524,288 B
    _Float16* w2t_hi  = (_Float16*)(ws + 51904512);           //     36,864 B
    _Float16* w2t_lo  = (_Float16*)(ws + 51941376);           //     36,864 B
    _Float16* fw_hi   = (_Float16*)(ws + 51978240);           //    200,704 B
    _Float16* fw_lo   = (_Float16*)(ws + 52178944);           //    200,704 B  (end 52,379,648)

    prep_weights<<<(18432 + 100352 + 255) / 256, 256, 0, stream>>>(
        w2, fw, w2t_hi, w2t_lo, fw_hi, fw_lo);
    conv_fused<<<N, 256, 0, stream>>>(x, w1, b1, w2t_hi, w2t_lo, b2, feat_hi, feat_lo);
    fc_mfma<<<256, 64, 0, stream>>>(feat_hi, feat_lo, fw_hi, fw_lo, fb, h);
    mlr_kernel<<<(N * 10 + 255) / 256, 256, 0, stream>>>(h, hw, hb, out);
}

// Round 5
// 168.004 us; speedup vs baseline: 11.6351x; 1.6250x over previous
//
#include <hip/hip_runtime.h>
#include <math.h>

#define EPSV 1e-5f

typedef _Float16 f16x8 __attribute__((ext_vector_type(8)));
typedef float f32x4 __attribute__((ext_vector_type(4)));

// ---------------------------------------------------------------------------
// Kernel 0: weight prep -> split-fp16 (hi,lo) pairs.
// w2t[off][oc][ic] (9,64,32) from w2 (64,32,3,3); fw (32,3136) row-major.
// ---------------------------------------------------------------------------
__global__ __launch_bounds__(256) void prep_weights(
    const float* __restrict__ w2, const float* __restrict__ fw,
    _Float16* __restrict__ w2t_hi, _Float16* __restrict__ w2t_lo,
    _Float16* __restrict__ fw_hi,  _Float16* __restrict__ fw_lo)
{
    int idx = blockIdx.x * 256 + threadIdx.x;
    if (idx < 18432) {
        int off = idx >> 11;            // /2048 (9*2048=18432)
        int rem = idx & 2047;
        int oc = rem >> 5, ic = rem & 31;
        float v = w2[(oc * 32 + ic) * 9 + off];
        _Float16 hx = (_Float16)v;
        w2t_hi[idx] = hx;
        w2t_lo[idx] = (_Float16)(v - (float)hx);
    } else if (idx < 18432 + 100352) {
        int j = idx - 18432;
        float v = fw[j];
        _Float16 hx = (_Float16)v;
        fw_hi[j] = hx;
        fw_lo[j] = (_Float16)(v - (float)hx);
    }
}

// ---------------------------------------------------------------------------
// conv2 half-pass: NROWS output rows starting at ROW0, taps outer (acc[NROWS]
// live, 2 A-frags live), pool pairs immediately -> F LDS. Split-fp16: 3 MFMA.
// ---------------------------------------------------------------------------
template<int ROW0, int NROWS, int P2OFF>
__device__ __forceinline__ void conv2_half(
    const _Float16* __restrict__ w2t_hi, const _Float16* __restrict__ w2t_lo,
    const _Float16* Bbuf_hi, const _Float16* Bbuf_lo,
    _Float16* Fhi, _Float16* Flo,
    int ocb, int cl, int kg, const float* bias, bool wlane, int px2)
{
    f32x4 acc[NROWS];
    #pragma unroll
    for (int r = 0; r < NROWS; ++r) acc[r] = (f32x4){0.f, 0.f, 0.f, 0.f};

    #pragma unroll 1                      // keep only 2 A-frags live
    for (int off = 0; off < 9; ++off) {
        int ky = off / 3, kx = off - ky * 3;
        f16x8 a_hi = *(const f16x8*)(w2t_hi + ((size_t)off * 64 + ocb + cl) * 32 + kg * 8);
        f16x8 a_lo = *(const f16x8*)(w2t_lo + ((size_t)off * 64 + ocb + cl) * 32 + kg * 8);
        const int base = (kg * 256 + (ROW0 + ky) * 16 + (cl + kx)) * 8;
        #pragma unroll
        for (int py = 0; py < NROWS; ++py) {
            f16x8 b_hi = *(const f16x8*)(Bbuf_hi + base + py * 128);
            f16x8 b_lo = *(const f16x8*)(Bbuf_lo + base + py * 128);
            acc[py] = __builtin_amdgcn_mfma_f32_16x16x32_f16(a_hi, b_hi, acc[py], 0, 0, 0);
            acc[py] = __builtin_amdgcn_mfma_f32_16x16x32_f16(a_lo, b_hi, acc[py], 0, 0, 0);
            acc[py] = __builtin_amdgcn_mfma_f32_16x16x32_f16(a_hi, b_lo, acc[py], 0, 0, 0);
        }
    }
    // Pool 2x2 in registers: horizontal partner = lane cl^1, vertical = acc pair
    #pragma unroll
    for (int p = 0; p < NROWS / 2; ++p) {
        f32x4 r0 = acc[2 * p], r1 = acc[2 * p + 1];
        #pragma unroll
        for (int r = 0; r < 4; ++r) {
            float v0 = fmaxf(r0[r], __shfl_xor(r0[r], 1));
            float v1 = fmaxf(r1[r], __shfl_xor(r1[r], 1));
            float m = fmaxf(fmaxf(v0, v1) + bias[r], 0.f);
            _Float16 mh = (_Float16)m;
            _Float16 ml = (_Float16)(m - (float)mh);
            if (wlane) {
                int o = (ocb + kg * 4 + r) * 49 + (P2OFF + p) * 7 + px2;
                Fhi[o] = mh; Flo[o] = ml;
            }
        }
    }
}

// ---------------------------------------------------------------------------
// Kernel 1: conv1(fp32)+relu+pool -> split-fp16 LDS -> conv2 via split MFMA ->
// register pool -> feat hi/lo. One block per image, 4 waves, 3 blocks/CU.
// LDS (48960 B): in_pad[900]f32 | Bbuf_hi 16K | Bbuf_lo 16K | pad | Fhi | Flo
// ---------------------------------------------------------------------------
__global__ __launch_bounds__(256, 3) void conv_fused(
    const float* __restrict__ x,       // (N,1,28,28)
    const float* __restrict__ w1,      // (32,1,3,3)
    const float* __restrict__ b1,      // (32,)
    const _Float16* __restrict__ w2t_hi, // (9,64,32)
    const _Float16* __restrict__ w2t_lo,
    const float* __restrict__ b2,      // (64,)
    _Float16* __restrict__ feat_hi,    // (N,3136)
    _Float16* __restrict__ feat_lo)    // (N,3136)
{
    __shared__ float4 smem4[3060];                        // 48960 B
    float*    in_pad  = (float*)smem4;                    // 3600 B
    _Float16* Bbuf_hi = (_Float16*)((char*)smem4 + 3600); // 16384 B
    _Float16* Bbuf_lo = (_Float16*)((char*)smem4 + 19984);// 16384 B (ends 36368)
    _Float16* Fhi     = (_Float16*)((char*)smem4 + 36416);// 6272 B
    _Float16* Flo     = (_Float16*)((char*)smem4 + 42688);// 6272 B (ends 48960)

    const int tid  = threadIdx.x;
    const int lane = tid & 63;
    const int wave = tid >> 6;
    const int kg   = lane >> 4;      // 0..3
    const int cl   = lane & 15;      // 0..15
    const int n    = blockIdx.x;

    // Phase AB (disjoint writes, single barrier after):
    //  - zero in_pad perimeter, stage x into interior
    //  - zero both Bbufs (8192 dwords contiguous)
    for (int i = tid; i < 116; i += 256) {
        int yy, xx;
        if (i < 30)       { yy = 0;         xx = i; }
        else if (i < 60)  { yy = 29;        xx = i - 30; }
        else if (i < 88)  { yy = i - 60 + 1; xx = 0; }
        else              { yy = i - 88 + 1; xx = 29; }
        in_pad[yy * 30 + xx] = 0.f;
    }
    const float* xin = x + (size_t)n * 784;
    for (int i = tid; i < 784; i += 256) {
        int yy = i / 28, xx = i - yy * 28;
        in_pad[(yy + 1) * 30 + (xx + 1)] = xin[i];
    }
    {
        int* zp = (int*)Bbuf_hi;
        for (int i = tid; i < 8192; i += 256) zp[i] = 0;
    }
    __syncthreads();

    // Phase C: conv1 + relu + pool -> Bbuf hi/lo (wave = ic-group, 8 ics/lane-pos)
    {
        const int icb = __builtin_amdgcn_readfirstlane(wave * 8);
        for (int r = 0; r < 4; ++r) {
            int pos = r * 64 + lane;                  // 0..195 valid
            bool valid = pos < 196;
            int posc = valid ? pos : 195;
            int py = posc / 14, px = posc - py * 14;
            float p[4][4];
            #pragma unroll
            for (int rr = 0; rr < 4; ++rr) {
                const float2* rp = (const float2*)&in_pad[(2 * py + rr) * 30 + 2 * px];
                float2 a = rp[0], b = rp[1];
                p[rr][0] = a.x; p[rr][1] = a.y; p[rr][2] = b.x; p[rr][3] = b.y;
            }
            f16x8 vhi, vlo;
            #pragma unroll
            for (int o = 0; o < 8; ++o) {
                const float* wv = w1 + (icb + o) * 9;    // wave-uniform -> s_load
                float bias = b1[icb + o];
                float m = 0.f;
                #pragma unroll
                for (int q = 0; q < 4; ++q) {
                    int dy = q >> 1, dx = q & 1;
                    float s = bias;
                    #pragma unroll
                    for (int ky = 0; ky < 3; ++ky)
                        #pragma unroll
                        for (int kx = 0; kx < 3; ++kx)
                            s += p[dy + ky][dx + kx] * wv[ky * 3 + kx];
                    m = fmaxf(m, s);
                }
                _Float16 hx = (_Float16)m;
                vhi[o] = hx;
                vlo[o] = (_Float16)(m - (float)hx);
            }
            if (valid) {
                int cell = (wave * 256 + (py + 1) * 16 + (px + 1)) * 8;
                *(f16x8*)(Bbuf_hi + cell) = vhi;
                *(f16x8*)(Bbuf_lo + cell) = vlo;
            }
        }
    }
    __syncthreads();

    // Phase D: conv2 in two half-passes (rows 0-7, 8-13), pool into F region.
    const int ocb = wave * 16;
    float bias[4];
    #pragma unroll
    for (int r = 0; r < 4; ++r) bias[r] = b2[ocb + kg * 4 + r];
    const bool wlane = ((cl & 1) == 0) && (cl < 14);
    const int px2 = cl >> 1;

    conv2_half<0, 8, 0>(w2t_hi, w2t_lo, Bbuf_hi, Bbuf_lo, Fhi, Flo,
                        ocb, cl, kg, bias, wlane, px2);
    conv2_half<8, 6, 4>(w2t_hi, w2t_lo, Bbuf_hi, Bbuf_lo, Fhi, Flo,
                        ocb, cl, kg, bias, wlane, px2);
    __syncthreads();

    // Coalesced dump: 1568 dwords per plane
    unsigned* gh = (unsigned*)(feat_hi + (size_t)n * 3136);
    unsigned* gl = (unsigned*)(feat_lo + (size_t)n * 3136);
    const unsigned* sh = (const unsigned*)Fhi;
    const unsigned* sl = (const unsigned*)Flo;
    for (int i = tid; i < 1568; i += 256) { gh[i] = sh[i]; gl[i] = sl[i]; }
}

// ---------------------------------------------------------------------------
// Kernel 2: fused FC (split-fp16 MFMA) + hyperbolic MLR head.
// 256 blocks x 256 threads. Block = 16-image M-tile; 4 waves split K
// (k-steps 25/25/24/24 of 98), combine in LDS, then MLR on the LDS h-tile.
// ---------------------------------------------------------------------------
__global__ __launch_bounds__(256) void fc_mlr(
    const _Float16* __restrict__ feat_hi, const _Float16* __restrict__ feat_lo,
    const _Float16* __restrict__ fw_hi,   const _Float16* __restrict__ fw_lo,
    const float* __restrict__ fb,
    const float* __restrict__ hw,   // (10,32)
    const float* __restrict__ hb,   // (10,32)
    float* __restrict__ out)        // (N,10)
{
    __shared__ float part[4][64][9];   // padded: stride 9 -> conflict-free
    __shared__ float Ht[16][33];

    const int tid  = threadIdx.x;
    const int lane = tid & 63;
    const int wave = tid >> 6;
    const int kg = lane >> 4, cl = lane & 15;
    const int m0 = blockIdx.x * 16;

    const int start = wave * 25 - (wave == 3 ? 1 : 0);   // 0,25,50,74
    const int nstep = (wave < 2) ? 25 : 24;
    const size_t koff = (size_t)start * 32 + kg * 8;

    const _Float16* ah  = feat_hi + (size_t)(m0 + cl) * 3136 + koff;
    const _Float16* al  = feat_lo + (size_t)(m0 + cl) * 3136 + koff;
    const _Float16* b0h = fw_hi + (size_t)cl * 3136 + koff;
    const _Float16* b0l = fw_lo + (size_t)cl * 3136 + koff;
    const _Float16* b1h = fw_hi + (size_t)(16 + cl) * 3136 + koff;
    const _Float16* b1l = fw_lo + (size_t)(16 + cl) * 3136 + koff;

    f32x4 acc0 = {0.f, 0.f, 0.f, 0.f}, acc1 = {0.f, 0.f, 0.f, 0.f};
    for (int s = 0; s < nstep; ++s) {
        int k0 = s * 32;
        f16x8 vah = *(const f16x8*)(ah + k0);
        f16x8 val_ = *(const f16x8*)(al + k0);
        f16x8 v0h = *(const f16x8*)(b0h + k0);
        f16x8 v0l = *(const f16x8*)(b0l + k0);
        f16x8 v1h = *(const f16x8*)(b1h + k0);
        f16x8 v1l = *(const f16x8*)(b1l + k0);
        acc0 = __builtin_amdgcn_mfma_f32_16x16x32_f16(vah, v0h, acc0, 0, 0, 0);
        acc0 = __builtin_amdgcn_mfma_f32_16x16x32_f16(val_, v0h, acc0, 0, 0, 0);
        acc0 = __builtin_amdgcn_mfma_f32_16x16x32_f16(vah, v0l, acc0, 0, 0, 0);
        acc1 = __builtin_amdgcn_mfma_f32_16x16x32_f16(vah, v1h, acc1, 0, 0, 0);
        acc1 = __builtin_amdgcn_mfma_f32_16x16x32_f16(val_, v1h, acc1, 0, 0, 0);
        acc1 = __builtin_amdgcn_mfma_f32_16x16x32_f16(vah, v1l, acc1, 0, 0, 0);
    }
    #pragma unroll
    for (int r = 0; r < 4; ++r) {
        part[wave][lane][r]     = acc0[r];
        part[wave][lane][4 + r] = acc1[r];
    }
    __syncthreads();

    // Reduce 4 partials -> h tile in LDS. 512 values, 2 per thread.
    #pragma unroll
    for (int jj = 0; jj < 2; ++jj) {
        int j = tid + jj * 256;
        int col = j & 31, row = j >> 5;                 // row = image 0..15
        int l  = ((row >> 2) << 4) + (col & 15);
        int rr = ((col >= 16) ? 4 : 0) + (row & 3);
        float s = part[0][l][rr] + part[1][l][rr] + part[2][l][rr] + part[3][l][rr];
        Ht[row][col] = s + fb[col];
    }
    __syncthreads();

    // MLR head: 160 outputs (16 images x 10 classes), fp32.
    if (tid < 160) {
        int im = tid / 10, k = tid - im * 10;
        const float* xr = &Ht[im][0];
        const float* wr = hw + k * 32;
        const float* br = hb + k * 32;
        float x2 = 0.f, b2s = 0.f, ww = 0.f, xb = 0.f, xw = 0.f, wb = 0.f;
        #pragma unroll
        for (int i = 0; i < 32; ++i) {
            float xi = xr[i], wi = wr[i], bi = br[i];
            x2 += xi * xi;  b2s += bi * bi;  ww += wi * wi;
            xb += xi * bi;  xw += xi * wi;   wb += wi * bi;
        }
        float w_norm = sqrtf(ww);
        float wnc = fmaxf(w_norm, 1e-12f);
        float inner = -xb;
        float a_num = 1.f + 2.f * inner + x2;
        float b_num = 1.f - b2s;
        float den = 1.f + 2.f * inner + x2 * b2s;
        float alpha = a_num / fmaxf(den, EPSV);
        float beta = b_num / den;                 // raw denom, as in source
        float mob2 = alpha * alpha * b2s + 2.f * alpha * beta * inner + beta * beta * x2;
        float sq = sqrtf(mob2);
        const float MAXN = (float)(1.0 - 1e-5);
        const float MAXN2 = (float)((1.0 - 1e-5) * (1.0 - 1e-5));
        float normalizer = (sq > MAXN) ? (MAXN / fmaxf(sq, EPSV)) : 1.f;
        float mob2c = (sq < MAXN) ? mob2 : MAXN2;
        float hyper = (alpha * (-wb) + beta * xw) / wnc;
        hyper *= normalizer;
        float asin_in = 2.f * hyper / fmaxf(1.f - mob2c, EPSV);
        float scaler = 2.f / fmaxf(1.f - b2s, EPSV);
        out[(size_t)m0 * 10 + tid] = scaler * w_norm * asinhf(asin_in);
    }
}

// ---------------------------------------------------------------------------
extern "C" void kernel_launch(void* const* d_in, const int* in_sizes, int n_in,
                              void* d_out, int out_size, void* d_ws, size_t ws_size,
                              hipStream_t stream) {
    const float* x   = (const float*)d_in[0];
    const float* w1  = (const float*)d_in[1];
    const float* b1  = (const float*)d_in[2];
    const float* w2  = (const float*)d_in[3];
    const float* b2  = (const float*)d_in[4];
    const float* fw  = (const float*)d_in[5];
    const float* fb  = (const float*)d_in[6];
    const float* hw  = (const float*)d_in[7];
    const float* hb  = (const float*)d_in[8];
    float* out = (float*)d_out;

    const int N = 4096;
    char* ws = (char*)d_ws;
    _Float16* feat_hi = (_Float16*)ws;                        // 25,690,112 B
    _Float16* feat_lo = (_Float16*)(ws + 25690112);           // 25,690,112 B
    _Float16* w2t_hi  = (_Float16*)(ws + 51380224);           //     36,864 B
    _Float16* w2t_lo  = (_Float16*)(ws + 51417088);           //     36,864 B
    _Float16* fw_hi   = (_Float16*)(ws + 51453952);           //    200,704 B
    _Float16* fw_lo   = (_Float16*)(ws + 51654656);           //    200,704 B (end 51,855,360)

    prep_weights<<<(18432 + 100352 + 255) / 256, 256, 0, stream>>>(
        w2, fw, w2t_hi, w2t_lo, fw_hi, fw_lo);
    conv_fused<<<N, 256, 0, stream>>>(x, w1, b1, w2t_hi, w2t_lo, b2, feat_hi, feat_lo);
    fc_mlr<<<N / 16, 256, 0, stream>>>(feat_hi, feat_lo, fw_hi, fw_lo, fb, hw, hb, out);
}

// Round 6
// 156.213 us; speedup vs baseline: 12.5134x; 1.0755x over previous
//
#include <hip/hip_runtime.h>
#include <math.h>

#define EPSV 1e-5f

typedef _Float16 f16x8 __attribute__((ext_vector_type(8)));
typedef _Float16 f16x4 __attribute__((ext_vector_type(4)));
typedef float f32x4 __attribute__((ext_vector_type(4)));

// ---------------------------------------------------------------------------
// Kernel 0: weight prep -> split-fp16 (hi,lo) pairs.
// w2t[off][oc][ic] (9,64,32); fw (32,3136); w1p[oc][k32] with taps 0-8 at k=0..8,
// bias at k=9, zeros k=10..31 (conv1-as-GEMM A operand, bias folded).
// ---------------------------------------------------------------------------
__global__ __launch_bounds__(256) void prep_weights(
    const float* __restrict__ w1, const float* __restrict__ b1,
    const float* __restrict__ w2, const float* __restrict__ fw,
    _Float16* __restrict__ w2t_hi, _Float16* __restrict__ w2t_lo,
    _Float16* __restrict__ fw_hi,  _Float16* __restrict__ fw_lo,
    _Float16* __restrict__ w1p_hi, _Float16* __restrict__ w1p_lo)
{
    int idx = blockIdx.x * 256 + threadIdx.x;
    if (idx < 18432) {
        int off = idx >> 11;            // /2048 (9*2048=18432)
        int rem = idx & 2047;
        int oc = rem >> 5, ic = rem & 31;
        float v = w2[(oc * 32 + ic) * 9 + off];
        _Float16 hx = (_Float16)v;
        w2t_hi[idx] = hx;
        w2t_lo[idx] = (_Float16)(v - (float)hx);
    } else if (idx < 18432 + 100352) {
        int j = idx - 18432;
        float v = fw[j];
        _Float16 hx = (_Float16)v;
        fw_hi[j] = hx;
        fw_lo[j] = (_Float16)(v - (float)hx);
    } else if (idx < 18432 + 100352 + 1024) {
        int j = idx - (18432 + 100352);
        int oc = j >> 5, k = j & 31;
        float v = (k < 9) ? w1[oc * 9 + k] : ((k == 9) ? b1[oc] : 0.f);
        _Float16 hx = (_Float16)v;
        w1p_hi[j] = hx;
        w1p_lo[j] = (_Float16)(v - (float)hx);
    }
}

// ---------------------------------------------------------------------------
// conv2 half-pass: NROWS output rows starting at ROW0, taps outer (acc[NROWS]
// live, 2 A-frags live), pool pairs immediately -> F LDS. Split-fp16: 3 MFMA.
// ---------------------------------------------------------------------------
template<int ROW0, int NROWS, int P2OFF>
__device__ __forceinline__ void conv2_half(
    const _Float16* __restrict__ w2t_hi, const _Float16* __restrict__ w2t_lo,
    const _Float16* Bbuf_hi, const _Float16* Bbuf_lo,
    _Float16* Fhi, _Float16* Flo,
    int ocb, int cl, int kg, const float* bias, bool wlane, int px2)
{
    f32x4 acc[NROWS];
    #pragma unroll
    for (int r = 0; r < NROWS; ++r) acc[r] = (f32x4){0.f, 0.f, 0.f, 0.f};

    #pragma unroll 1                      // keep only 2 A-frags live
    for (int off = 0; off < 9; ++off) {
        int ky = off / 3, kx = off - ky * 3;
        f16x8 a_hi = *(const f16x8*)(w2t_hi + ((size_t)off * 64 + ocb + cl) * 32 + kg * 8);
        f16x8 a_lo = *(const f16x8*)(w2t_lo + ((size_t)off * 64 + ocb + cl) * 32 + kg * 8);
        const int base = (kg * 256 + (ROW0 + ky) * 16 + (cl + kx)) * 8;
        #pragma unroll
        for (int py = 0; py < NROWS; ++py) {
            f16x8 b_hi = *(const f16x8*)(Bbuf_hi + base + py * 128);
            f16x8 b_lo = *(const f16x8*)(Bbuf_lo + base + py * 128);
            acc[py] = __builtin_amdgcn_mfma_f32_16x16x32_f16(a_hi, b_hi, acc[py], 0, 0, 0);
            acc[py] = __builtin_amdgcn_mfma_f32_16x16x32_f16(a_lo, b_hi, acc[py], 0, 0, 0);
            acc[py] = __builtin_amdgcn_mfma_f32_16x16x32_f16(a_hi, b_lo, acc[py], 0, 0, 0);
        }
    }
    // Pool 2x2 in registers: horizontal partner = lane cl^1, vertical = acc pair
    #pragma unroll
    for (int p = 0; p < NROWS / 2; ++p) {
        f32x4 r0 = acc[2 * p], r1 = acc[2 * p + 1];
        #pragma unroll
        for (int r = 0; r < 4; ++r) {
            float v0 = fmaxf(r0[r], __shfl_xor(r0[r], 1));
            float v1 = fmaxf(r1[r], __shfl_xor(r1[r], 1));
            float m = fmaxf(fmaxf(v0, v1) + bias[r], 0.f);
            _Float16 mh = (_Float16)m;
            _Float16 ml = (_Float16)(m - (float)mh);
            if (wlane) {
                int o = (ocb + kg * 4 + r) * 49 + (P2OFF + p) * 7 + px2;
                Fhi[o] = mh; Flo[o] = ml;
            }
        }
    }
}

// ---------------------------------------------------------------------------
// Kernel 1: conv1 AND conv2 both via split-fp16 MFMA.
// conv1-as-GEMM: A = w1p (32oc x K32: taps+bias), B built per conv row from
// pre-split in_pad (u32 = hi|lo<<16). N-tile = one 28-wide conv row half (14
// cols + 2 dead). Pool in regs -> packed ds_write_b64 into conv2 staging.
// One block per image, 4 waves, 3 blocks/CU (LDS-limited).
// LDS (48960 B): in_pad u32[900] | Bbuf_hi 16K | Bbuf_lo 16K | pad | Fhi | Flo
// ---------------------------------------------------------------------------
__global__ __launch_bounds__(256, 3) void conv_fused(
    const float* __restrict__ x,         // (N,1,28,28)
    const _Float16* __restrict__ w1p_hi, // (32,32) taps+bias, K-padded
    const _Float16* __restrict__ w1p_lo,
    const _Float16* __restrict__ w2t_hi, // (9,64,32)
    const _Float16* __restrict__ w2t_lo,
    const float* __restrict__ b2,        // (64,)
    _Float16* __restrict__ feat_hi,      // (N,3136)
    _Float16* __restrict__ feat_lo)      // (N,3136)
{
    __shared__ float4 smem4[3060];                        // 48960 B
    unsigned* in_pad  = (unsigned*)smem4;                 // 900 u32 (hi|lo<<16)
    _Float16* Bbuf_hi = (_Float16*)((char*)smem4 + 3600); // 16384 B
    _Float16* Bbuf_lo = (_Float16*)((char*)smem4 + 19984);// 16384 B (ends 36368)
    _Float16* Fhi     = (_Float16*)((char*)smem4 + 36416);// 6272 B
    _Float16* Flo     = (_Float16*)((char*)smem4 + 42688);// 6272 B (ends 48960)

    const int tid  = threadIdx.x;
    const int lane = tid & 63;
    const int wave = tid >> 6;
    const int kg   = lane >> 4;      // 0..3
    const int cl   = lane & 15;      // 0..15
    const int n    = blockIdx.x;

    // Phase AB: zero in_pad perimeter; stage x interior pre-split; zero Bbufs.
    for (int i = tid; i < 116; i += 256) {
        int yy, xx;
        if (i < 30)       { yy = 0;          xx = i; }
        else if (i < 60)  { yy = 29;         xx = i - 30; }
        else if (i < 88)  { yy = i - 60 + 1; xx = 0; }
        else              { yy = i - 88 + 1; xx = 29; }
        in_pad[yy * 30 + xx] = 0u;
    }
    const float* xin = x + (size_t)n * 784;
    for (int i = tid; i < 784; i += 256) {
        int yy = i / 28, xx = i - yy * 28;
        float v = xin[i];
        _Float16 hx = (_Float16)v;
        _Float16 lx = (_Float16)(v - (float)hx);
        unsigned hb = *(const unsigned short*)&hx;
        unsigned lb = *(const unsigned short*)&lx;
        in_pad[(yy + 1) * 30 + (xx + 1)] = hb | (lb << 16);
    }
    {
        int* zp = (int*)Bbuf_hi;
        for (int i = tid; i < 8192; i += 256) zp[i] = 0;
    }
    __syncthreads();

    // Phase C: conv1 via MFMA. A[row=oc][k]: taps 0-8, bias slot k=9.
    // B[k][col=pos]: built per conv row from in_pad. Pool -> Bbuf staging.
    {
        f16x8 a1h[2], a1l[2];
        #pragma unroll
        for (int m = 0; m < 2; ++m) {
            a1h[m] = *(const f16x8*)(w1p_hi + (m * 16 + cl) * 32 + kg * 8);
            a1l[m] = *(const f16x8*)(w1p_lo + (m * 16 + cl) * 32 + kg * 8);
        }
        // per-lane tap offsets (k = kg*8+j): kg0 -> taps 0..7, kg1 j0 -> tap 8
        const int o0 = (kg == 0) ? 0  : ((kg == 1) ? 62 : 0);
        const int o1 = (kg == 0) ? 1  : 0;
        const int o2 = (kg == 0) ? 2  : 0;
        const int o3 = (kg == 0) ? 30 : 0;
        const int o4 = (kg == 0) ? 31 : 0;
        const int o5 = (kg == 0) ? 32 : 0;
        const int o6 = (kg == 0) ? 60 : 0;
        const int o7 = (kg == 0) ? 61 : 0;

        const bool wr = ((cl & 1) == 0) && (cl < 14);

        #pragma unroll 1
        for (int rp = wave; rp < 14; rp += 4) {       // pooled row rp
            #pragma unroll
            for (int hx = 0; hx < 2; ++hx) {          // row half
                const int xcol = hx * 14 + cl;
                f16x8 bh[2], bl[2];
                #pragma unroll
                for (int r2 = 0; r2 < 2; ++r2) {      // conv rows 2rp, 2rp+1
                    const int base = (2 * rp + r2) * 30 + xcol;
                    unsigned v0 = in_pad[base + o0], v1 = in_pad[base + o1];
                    unsigned v2 = in_pad[base + o2], v3 = in_pad[base + o3];
                    unsigned v4 = in_pad[base + o4], v5 = in_pad[base + o5];
                    unsigned v6 = in_pad[base + o6], v7 = in_pad[base + o7];
                    unsigned h01 = (v0 & 0xFFFFu) | (v1 << 16);
                    unsigned h23 = (v2 & 0xFFFFu) | (v3 << 16);
                    unsigned h45 = (v4 & 0xFFFFu) | (v5 << 16);
                    unsigned h67 = (v6 & 0xFFFFu) | (v7 << 16);
                    unsigned l01 = (v0 >> 16) | (v1 & 0xFFFF0000u);
                    unsigned l23 = (v2 >> 16) | (v3 & 0xFFFF0000u);
                    unsigned l45 = (v4 >> 16) | (v5 & 0xFFFF0000u);
                    unsigned l67 = (v6 >> 16) | (v7 & 0xFFFF0000u);
                    if (kg == 1) {
                        h01 = (h01 & 0xFFFFu) | 0x3C000000u;   // k=9: B_hi=1.0
                        l01 = (l01 & 0xFFFFu);                 //        B_lo=0
                        h23 = h45 = h67 = 0u; l23 = l45 = l67 = 0u;
                    } else if (kg >= 2) {
                        h01 = h23 = h45 = h67 = 0u;
                        l01 = l23 = l45 = l67 = 0u;
                    }
                    union { unsigned u[4]; f16x8 v; } uh, ul;
                    uh.u[0] = h01; uh.u[1] = h23; uh.u[2] = h45; uh.u[3] = h67;
                    ul.u[0] = l01; ul.u[1] = l23; ul.u[2] = l45; ul.u[3] = l67;
                    bh[r2] = uh.v; bl[r2] = ul.v;
                }
                #pragma unroll
                for (int m = 0; m < 2; ++m) {
                    f32x4 a0 = (f32x4){0.f, 0.f, 0.f, 0.f};
                    f32x4 a1 = (f32x4){0.f, 0.f, 0.f, 0.f};
                    a0 = __builtin_amdgcn_mfma_f32_16x16x32_f16(a1h[m], bh[0], a0, 0, 0, 0);
                    a0 = __builtin_amdgcn_mfma_f32_16x16x32_f16(a1l[m], bh[0], a0, 0, 0, 0);
                    a0 = __builtin_amdgcn_mfma_f32_16x16x32_f16(a1h[m], bl[0], a0, 0, 0, 0);
                    a1 = __builtin_amdgcn_mfma_f32_16x16x32_f16(a1h[m], bh[1], a1, 0, 0, 0);
                    a1 = __builtin_amdgcn_mfma_f32_16x16x32_f16(a1l[m], bh[1], a1, 0, 0, 0);
                    a1 = __builtin_amdgcn_mfma_f32_16x16x32_f16(a1h[m], bl[1], a1, 0, 0, 0);
                    // Pool (relu; bias already folded via k=9 slot)
                    float pv[4];
                    #pragma unroll
                    for (int r = 0; r < 4; ++r) {
                        float vp = fmaxf(a0[r], a1[r]);
                        float hp = fmaxf(vp, __shfl_xor(vp, 1));
                        pv[r] = fmaxf(hp, 0.f);
                    }
                    union { unsigned short s[4]; f16x4 v; } ph, pl;
                    #pragma unroll
                    for (int r = 0; r < 4; ++r) {
                        _Float16 mh = (_Float16)pv[r];
                        _Float16 ml = (_Float16)(pv[r] - (float)mh);
                        ph.s[r] = *(const unsigned short*)&mh;
                        pl.s[r] = *(const unsigned short*)&ml;
                    }
                    if (wr) {
                        // oc = m*16 + kg*4 + r -> icg = m*2+(kg>>1), slot = (kg&1)*4+r
                        const int px2 = hx * 7 + (cl >> 1);
                        const int cell = ((m * 2 + (kg >> 1)) * 256 +
                                          (rp + 1) * 16 + (px2 + 1)) * 8 + (kg & 1) * 4;
                        *(f16x4*)(Bbuf_hi + cell) = ph.v;
                        *(f16x4*)(Bbuf_lo + cell) = pl.v;
                    }
                }
            }
        }
    }
    __syncthreads();

    // Phase D: conv2 in two half-passes (rows 0-7, 8-13), pool into F region.
    const int ocb = wave * 16;
    float bias[4];
    #pragma unroll
    for (int r = 0; r < 4; ++r) bias[r] = b2[ocb + kg * 4 + r];
    const bool wlane = ((cl & 1) == 0) && (cl < 14);
    const int px2 = cl >> 1;

    conv2_half<0, 8, 0>(w2t_hi, w2t_lo, Bbuf_hi, Bbuf_lo, Fhi, Flo,
                        ocb, cl, kg, bias, wlane, px2);
    conv2_half<8, 6, 4>(w2t_hi, w2t_lo, Bbuf_hi, Bbuf_lo, Fhi, Flo,
                        ocb, cl, kg, bias, wlane, px2);
    __syncthreads();

    // Coalesced dump: 1568 dwords per plane
    unsigned* gh = (unsigned*)(feat_hi + (size_t)n * 3136);
    unsigned* gl = (unsigned*)(feat_lo + (size_t)n * 3136);
    const unsigned* sh = (const unsigned*)Fhi;
    const unsigned* sl = (const unsigned*)Flo;
    for (int i = tid; i < 1568; i += 256) { gh[i] = sh[i]; gl[i] = sl[i]; }
}

// ---------------------------------------------------------------------------
// Kernel 2: fused FC (split-fp16 MFMA) + hyperbolic MLR head.
// 256 blocks x 256 threads. Block = 16-image M-tile; 4 waves split K
// (k-steps 25/25/24/24 of 98), combine in LDS, then MLR on the LDS h-tile.
// ---------------------------------------------------------------------------
__global__ __launch_bounds__(256) void fc_mlr(
    const _Float16* __restrict__ feat_hi, const _Float16* __restrict__ feat_lo,
    const _Float16* __restrict__ fw_hi,   const _Float16* __restrict__ fw_lo,
    const float* __restrict__ fb,
    const float* __restrict__ hw,   // (10,32)
    const float* __restrict__ hb,   // (10,32)
    float* __restrict__ out)        // (N,10)
{
    __shared__ float part[4][64][9];   // padded: stride 9 -> conflict-free
    __shared__ float Ht[16][33];

    const int tid  = threadIdx.x;
    const int lane = tid & 63;
    const int wave = tid >> 6;
    const int kg = lane >> 4, cl = lane & 15;
    const int m0 = blockIdx.x * 16;

    const int start = wave * 25 - (wave == 3 ? 1 : 0);   // 0,25,50,74
    const int nstep = (wave < 2) ? 25 : 24;
    const size_t koff = (size_t)start * 32 + kg * 8;

    const _Float16* ah  = feat_hi + (size_t)(m0 + cl) * 3136 + koff;
    const _Float16* al  = feat_lo + (size_t)(m0 + cl) * 3136 + koff;
    const _Float16* b0h = fw_hi + (size_t)cl * 3136 + koff;
    const _Float16* b0l = fw_lo + (size_t)cl * 3136 + koff;
    const _Float16* b1h = fw_hi + (size_t)(16 + cl) * 3136 + koff;
    const _Float16* b1l = fw_lo + (size_t)(16 + cl) * 3136 + koff;

    f32x4 acc0 = {0.f, 0.f, 0.f, 0.f}, acc1 = {0.f, 0.f, 0.f, 0.f};
    for (int s = 0; s < nstep; ++s) {
        int k0 = s * 32;
        f16x8 vah = *(const f16x8*)(ah + k0);
        f16x8 val_ = *(const f16x8*)(al + k0);
        f16x8 v0h = *(const f16x8*)(b0h + k0);
        f16x8 v0l = *(const f16x8*)(b0l + k0);
        f16x8 v1h = *(const f16x8*)(b1h + k0);
        f16x8 v1l = *(const f16x8*)(b1l + k0);
        acc0 = __builtin_amdgcn_mfma_f32_16x16x32_f16(vah, v0h, acc0, 0, 0, 0);
        acc0 = __builtin_amdgcn_mfma_f32_16x16x32_f16(val_, v0h, acc0, 0, 0, 0);
        acc0 = __builtin_amdgcn_mfma_f32_16x16x32_f16(vah, v0l, acc0, 0, 0, 0);
        acc1 = __builtin_amdgcn_mfma_f32_16x16x32_f16(vah, v1h, acc1, 0, 0, 0);
        acc1 = __builtin_amdgcn_mfma_f32_16x16x32_f16(val_, v1h, acc1, 0, 0, 0);
        acc1 = __builtin_amdgcn_mfma_f32_16x16x32_f16(vah, v1l, acc1, 0, 0, 0);
    }
    #pragma unroll
    for (int r = 0; r < 4; ++r) {
        part[wave][lane][r]     = acc0[r];
        part[wave][lane][4 + r] = acc1[r];
    }
    __syncthreads();

    // Reduce 4 partials -> h tile in LDS. 512 values, 2 per thread.
    #pragma unroll
    for (int jj = 0; jj < 2; ++jj) {
        int j = tid + jj * 256;
        int col = j & 31, row = j >> 5;                 // row = image 0..15
        int l  = ((row >> 2) << 4) + (col & 15);
        int rr = ((col >= 16) ? 4 : 0) + (row & 3);
        float s = part[0][l][rr] + part[1][l][rr] + part[2][l][rr] + part[3][l][rr];
        Ht[row][col] = s + fb[col];
    }
    __syncthreads();

    // MLR head: 160 outputs (16 images x 10 classes), fp32.
    if (tid < 160) {
        int im = tid / 10, k = tid - im * 10;
        const float* xr = &Ht[im][0];
        const float* wr = hw + k * 32;
        const float* br = hb + k * 32;
        float x2 = 0.f, b2s = 0.f, ww = 0.f, xb = 0.f, xw = 0.f, wb = 0.f;
        #pragma unroll
        for (int i = 0; i < 32; ++i) {
            float xi = xr[i], wi = wr[i], bi = br[i];
            x2 += xi * xi;  b2s += bi * bi;  ww += wi * wi;
            xb += xi * bi;  xw += xi * wi;   wb += wi * bi;
        }
        float w_norm = sqrtf(ww);
        float wnc = fmaxf(w_norm, 1e-12f);
        float inner = -xb;
        float a_num = 1.f + 2.f * inner + x2;
        float b_num = 1.f - b2s;
        float den = 1.f + 2.f * inner + x2 * b2s;
        float alpha = a_num / fmaxf(den, EPSV);
        float beta = b_num / den;                 // raw denom, as in source
        float mob2 = alpha * alpha * b2s + 2.f * alpha * beta * inner + beta * beta * x2;
        float sq = sqrtf(mob2);
        const float MAXN = (float)(1.0 - 1e-5);
        const float MAXN2 = (float)((1.0 - 1e-5) * (1.0 - 1e-5));
        float normalizer = (sq > MAXN) ? (MAXN / fmaxf(sq, EPSV)) : 1.f;
        float mob2c = (sq < MAXN) ? mob2 : MAXN2;
        float hyper = (alpha * (-wb) + beta * xw) / wnc;
        hyper *= normalizer;
        float asin_in = 2.f * hyper / fmaxf(1.f - mob2c, EPSV);
        float scaler = 2.f / fmaxf(1.f - b2s, EPSV);
        out[(size_t)m0 * 10 + tid] = scaler * w_norm * asinhf(asin_in);
    }
}

// ---------------------------------------------------------------------------
extern "C" void kernel_launch(void* const* d_in, const int* in_sizes, int n_in,
                              void* d_out, int out_size, void* d_ws, size_t ws_size,
                              hipStream_t stream) {
    const float* x   = (const float*)d_in[0];
    const float* w1  = (const float*)d_in[1];
    const float* b1  = (const float*)d_in[2];
    const float* w2  = (const float*)d_in[3];
    const float* b2  = (const float*)d_in[4];
    const float* fw  = (const float*)d_in[5];
    const float* fb  = (const float*)d_in[6];
    const float* hw  = (const float*)d_in[7];
    const float* hb  = (const float*)d_in[8];
    float* out = (float*)d_out;

    const int N = 4096;
    char* ws = (char*)d_ws;
    _Float16* feat_hi = (_Float16*)ws;                        // 25,690,112 B
    _Float16* feat_lo = (_Float16*)(ws + 25690112);           // 25,690,112 B
    _Float16* w2t_hi  = (_Float16*)(ws + 51380224);           //     36,864 B
    _Float16* w2t_lo  = (_Float16*)(ws + 51417088);           //     36,864 B
    _Float16* fw_hi   = (_Float16*)(ws + 51453952);           //    200,704 B
    _Float16* fw_lo   = (_Float16*)(ws + 51654656);           //    200,704 B
    _Float16* w1p_hi  = (_Float16*)(ws + 51855360);           //      2,048 B
    _Float16* w1p_lo  = (_Float16*)(ws + 51857408);           //      2,048 B (end 51,859,456)

    prep_weights<<<(18432 + 100352 + 1024 + 255) / 256, 256, 0, stream>>>(
        w1, b1, w2, fw, w2t_hi, w2t_lo, fw_hi, fw_lo, w1p_hi, w1p_lo);
    conv_fused<<<N, 256, 0, stream>>>(x, w1p_hi, w1p_lo, w2t_hi, w2t_lo, b2,
                                      feat_hi, feat_lo);
    fc_mlr<<<N / 16, 256, 0, stream>>>(feat_hi, feat_lo, fw_hi, fw_lo, fb, hw, hb, out);
}

// Round 7
// 141.756 us; speedup vs baseline: 13.7896x; 1.1020x over previous
//
#include <hip/hip_runtime.h>
#include <math.h>

#define EPSV 1e-5f

typedef _Float16 f16x8 __attribute__((ext_vector_type(8)));
typedef _Float16 f16x4 __attribute__((ext_vector_type(4)));
typedef float f32x4 __attribute__((ext_vector_type(4)));

// ---------------------------------------------------------------------------
// Kernel 0: weight prep -> split-fp16 (hi,lo) pairs.
// w2t[off][oc][ic] (9,64,32); fw (32,3136); w1p[oc][k32] taps 0-8, bias k=9.
// ---------------------------------------------------------------------------
__global__ __launch_bounds__(256) void prep_weights(
    const float* __restrict__ w1, const float* __restrict__ b1,
    const float* __restrict__ w2, const float* __restrict__ fw,
    _Float16* __restrict__ w2t_hi, _Float16* __restrict__ w2t_lo,
    _Float16* __restrict__ fw_hi,  _Float16* __restrict__ fw_lo,
    _Float16* __restrict__ w1p_hi, _Float16* __restrict__ w1p_lo)
{
    int idx = blockIdx.x * 256 + threadIdx.x;
    if (idx < 18432) {
        int off = idx >> 11;            // /2048 (9*2048=18432)
        int rem = idx & 2047;
        int oc = rem >> 5, ic = rem & 31;
        float v = w2[(oc * 32 + ic) * 9 + off];
        _Float16 hx = (_Float16)v;
        w2t_hi[idx] = hx;
        w2t_lo[idx] = (_Float16)(v - (float)hx);
    } else if (idx < 18432 + 100352) {
        int j = idx - 18432;
        float v = fw[j];
        _Float16 hx = (_Float16)v;
        fw_hi[j] = hx;
        fw_lo[j] = (_Float16)(v - (float)hx);
    } else if (idx < 18432 + 100352 + 1024) {
        int j = idx - (18432 + 100352);
        int oc = j >> 5, k = j & 31;
        float v = (k < 9) ? w1[oc * 9 + k] : ((k == 9) ? b1[oc] : 0.f);
        _Float16 hx = (_Float16)v;
        w1p_hi[j] = hx;
        w1p_lo[j] = (_Float16)(v - (float)hx);
    }
}

// ---------------------------------------------------------------------------
// conv2 half-pass: NROWS rows from ROW0, taps outer (2 A-frags live), pool
// 2x2 in registers -> pool[NROWS/2][4] floats. No LDS writes here.
// ---------------------------------------------------------------------------
template<int ROW0, int NROWS>
__device__ __forceinline__ void conv2_half(
    const _Float16* __restrict__ w2t_hi, const _Float16* __restrict__ w2t_lo,
    const _Float16* Bbuf_hi, const _Float16* Bbuf_lo,
    int ocb, int cl, int kg, const float* bias, float pool[][4])
{
    f32x4 acc[NROWS];
    #pragma unroll
    for (int r = 0; r < NROWS; ++r) acc[r] = (f32x4){0.f, 0.f, 0.f, 0.f};

    #pragma unroll 1                      // keep only 2 A-frags live
    for (int off = 0; off < 9; ++off) {
        int ky = off / 3, kx = off - ky * 3;
        f16x8 a_hi = *(const f16x8*)(w2t_hi + ((size_t)off * 64 + ocb + cl) * 32 + kg * 8);
        f16x8 a_lo = *(const f16x8*)(w2t_lo + ((size_t)off * 64 + ocb + cl) * 32 + kg * 8);
        const int base = (kg * 256 + (ROW0 + ky) * 16 + (cl + kx)) * 8;
        #pragma unroll
        for (int py = 0; py < NROWS; ++py) {
            f16x8 b_hi = *(const f16x8*)(Bbuf_hi + base + py * 128);
            f16x8 b_lo = *(const f16x8*)(Bbuf_lo + base + py * 128);
            acc[py] = __builtin_amdgcn_mfma_f32_16x16x32_f16(a_hi, b_hi, acc[py], 0, 0, 0);
            acc[py] = __builtin_amdgcn_mfma_f32_16x16x32_f16(a_lo, b_hi, acc[py], 0, 0, 0);
            acc[py] = __builtin_amdgcn_mfma_f32_16x16x32_f16(a_hi, b_lo, acc[py], 0, 0, 0);
        }
    }
    // Pool 2x2: horizontal partner = lane cl^1, vertical = acc pair
    #pragma unroll
    for (int p = 0; p < NROWS / 2; ++p) {
        f32x4 r0 = acc[2 * p], r1 = acc[2 * p + 1];
        #pragma unroll
        for (int r = 0; r < 4; ++r) {
            float v0 = fmaxf(r0[r], __shfl_xor(r0[r], 1));
            float v1 = fmaxf(r1[r], __shfl_xor(r1[r], 1));
            pool[p][r] = fmaxf(fmaxf(v0, v1) + bias[r], 0.f);
        }
    }
}

// ---------------------------------------------------------------------------
// Kernel 1: conv1 AND conv2 via split-fp16 MFMA. One block per image, 4 waves,
// 4 blocks/CU. LDS 36416 B: in_pad u32[900] | Bbuf_hi 16K | Bbuf_lo 16K | pad.
// F staging (12544 B) aliases the base after conv2 reads complete.
// Bbuf zeroing: padding ring only (interior fully written by phase C).
// ---------------------------------------------------------------------------
__global__ __launch_bounds__(256, 4) void conv_fused(
    const float* __restrict__ x,         // (N,1,28,28)
    const _Float16* __restrict__ w1p_hi, // (32,32) taps+bias, K-padded
    const _Float16* __restrict__ w1p_lo,
    const _Float16* __restrict__ w2t_hi, // (9,64,32)
    const _Float16* __restrict__ w2t_lo,
    const float* __restrict__ b2,        // (64,)
    _Float16* __restrict__ feat_hi,      // (N,3136)
    _Float16* __restrict__ feat_lo)      // (N,3136)
{
    __shared__ float4 smem4[2276];                        // 36416 B
    unsigned* in_pad  = (unsigned*)smem4;                 // 900 u32 (hi|lo<<16)
    _Float16* Bbuf_hi = (_Float16*)((char*)smem4 + 3600); // 16384 B
    _Float16* Bbuf_lo = (_Float16*)((char*)smem4 + 19984);// 16384 B (ends 36368, +48 pad)
    _Float16* Fhi     = (_Float16*)smem4;                 // 6272 B (aliased, post-barrier)
    _Float16* Flo     = Fhi + 3136;                       // 6272 B (ends 12544)

    const int tid  = threadIdx.x;
    const int lane = tid & 63;
    const int wave = tid >> 6;
    const int kg   = lane >> 4;      // 0..3
    const int cl   = lane & 15;      // 0..15
    const int n    = blockIdx.x;

    // Phase AB: zero in_pad perimeter; stage x interior pre-split;
    // zero Bbuf padding ring (60 cells x 4 icg).
    for (int i = tid; i < 116; i += 256) {
        int yy, xx;
        if (i < 30)       { yy = 0;          xx = i; }
        else if (i < 60)  { yy = 29;         xx = i - 30; }
        else if (i < 88)  { yy = i - 60 + 1; xx = 0; }
        else              { yy = i - 88 + 1; xx = 29; }
        in_pad[yy * 30 + xx] = 0u;
    }
    const float* xin = x + (size_t)n * 784;
    for (int i = tid; i < 784; i += 256) {
        int yy = i / 28, xx = i - yy * 28;
        float v = xin[i];
        _Float16 hx = (_Float16)v;
        _Float16 lx = (_Float16)(v - (float)hx);
        unsigned hb = *(const unsigned short*)&hx;
        unsigned lb = *(const unsigned short*)&lx;
        in_pad[(yy + 1) * 30 + (xx + 1)] = hb | (lb << 16);
    }
    if (tid < 240) {
        int icg = tid / 60, j = tid - icg * 60;
        int row, col;
        if (j < 16)      { row = 0;      col = j; }
        else if (j < 32) { row = 15;     col = j - 16; }
        else if (j < 46) { row = j - 31; col = 0; }
        else             { row = j - 45; col = 15; }
        int c = (icg * 256 + row * 16 + col) * 8;
        *(f32x4*)(Bbuf_hi + c) = (f32x4){0.f, 0.f, 0.f, 0.f};
        *(f32x4*)(Bbuf_lo + c) = (f32x4){0.f, 0.f, 0.f, 0.f};
    }
    __syncthreads();

    // Phase C: conv1 via MFMA (A = w1p taps+bias; B built from pre-split in_pad).
    {
        f16x8 a1h[2], a1l[2];
        #pragma unroll
        for (int m = 0; m < 2; ++m) {
            a1h[m] = *(const f16x8*)(w1p_hi + (m * 16 + cl) * 32 + kg * 8);
            a1l[m] = *(const f16x8*)(w1p_lo + (m * 16 + cl) * 32 + kg * 8);
        }
        const int o0 = (kg == 0) ? 0  : ((kg == 1) ? 62 : 0);
        const int o1 = (kg == 0) ? 1  : 0;
        const int o2 = (kg == 0) ? 2  : 0;
        const int o3 = (kg == 0) ? 30 : 0;
        const int o4 = (kg == 0) ? 31 : 0;
        const int o5 = (kg == 0) ? 32 : 0;
        const int o6 = (kg == 0) ? 60 : 0;
        const int o7 = (kg == 0) ? 61 : 0;

        const bool wr = ((cl & 1) == 0) && (cl < 14);

        #pragma unroll 1
        for (int rp = wave; rp < 14; rp += 4) {       // pooled row rp
            #pragma unroll
            for (int hx = 0; hx < 2; ++hx) {          // row half
                const int xcol = hx * 14 + cl;
                f16x8 bh[2], bl[2];
                #pragma unroll
                for (int r2 = 0; r2 < 2; ++r2) {      // conv rows 2rp, 2rp+1
                    const int base = (2 * rp + r2) * 30 + xcol;
                    unsigned v0 = in_pad[base + o0], v1 = in_pad[base + o1];
                    unsigned v2 = in_pad[base + o2], v3 = in_pad[base + o3];
                    unsigned v4 = in_pad[base + o4], v5 = in_pad[base + o5];
                    unsigned v6 = in_pad[base + o6], v7 = in_pad[base + o7];
                    unsigned h01 = (v0 & 0xFFFFu) | (v1 << 16);
                    unsigned h23 = (v2 & 0xFFFFu) | (v3 << 16);
                    unsigned h45 = (v4 & 0xFFFFu) | (v5 << 16);
                    unsigned h67 = (v6 & 0xFFFFu) | (v7 << 16);
                    unsigned l01 = (v0 >> 16) | (v1 & 0xFFFF0000u);
                    unsigned l23 = (v2 >> 16) | (v3 & 0xFFFF0000u);
                    unsigned l45 = (v4 >> 16) | (v5 & 0xFFFF0000u);
                    unsigned l67 = (v6 >> 16) | (v7 & 0xFFFF0000u);
                    if (kg == 1) {
                        h01 = (h01 & 0xFFFFu) | 0x3C000000u;   // k=9: B_hi=1.0
                        l01 = (l01 & 0xFFFFu);                 //        B_lo=0
                        h23 = h45 = h67 = 0u; l23 = l45 = l67 = 0u;
                    } else if (kg >= 2) {
                        h01 = h23 = h45 = h67 = 0u;
                        l01 = l23 = l45 = l67 = 0u;
                    }
                    union { unsigned u[4]; f16x8 v; } uh, ul;
                    uh.u[0] = h01; uh.u[1] = h23; uh.u[2] = h45; uh.u[3] = h67;
                    ul.u[0] = l01; ul.u[1] = l23; ul.u[2] = l45; ul.u[3] = l67;
                    bh[r2] = uh.v; bl[r2] = ul.v;
                }
                #pragma unroll
                for (int m = 0; m < 2; ++m) {
                    f32x4 a0 = (f32x4){0.f, 0.f, 0.f, 0.f};
                    f32x4 a1 = (f32x4){0.f, 0.f, 0.f, 0.f};
                    a0 = __builtin_amdgcn_mfma_f32_16x16x32_f16(a1h[m], bh[0], a0, 0, 0, 0);
                    a0 = __builtin_amdgcn_mfma_f32_16x16x32_f16(a1l[m], bh[0], a0, 0, 0, 0);
                    a0 = __builtin_amdgcn_mfma_f32_16x16x32_f16(a1h[m], bl[0], a0, 0, 0, 0);
                    a1 = __builtin_amdgcn_mfma_f32_16x16x32_f16(a1h[m], bh[1], a1, 0, 0, 0);
                    a1 = __builtin_amdgcn_mfma_f32_16x16x32_f16(a1l[m], bh[1], a1, 0, 0, 0);
                    a1 = __builtin_amdgcn_mfma_f32_16x16x32_f16(a1h[m], bl[1], a1, 0, 0, 0);
                    float pv[4];
                    #pragma unroll
                    for (int r = 0; r < 4; ++r) {
                        float vp = fmaxf(a0[r], a1[r]);
                        float hp = fmaxf(vp, __shfl_xor(vp, 1));
                        pv[r] = fmaxf(hp, 0.f);
                    }
                    union { unsigned short s[4]; f16x4 v; } ph, pl;
                    #pragma unroll
                    for (int r = 0; r < 4; ++r) {
                        _Float16 mh = (_Float16)pv[r];
                        _Float16 ml = (_Float16)(pv[r] - (float)mh);
                        ph.s[r] = *(const unsigned short*)&mh;
                        pl.s[r] = *(const unsigned short*)&ml;
                    }
                    if (wr) {
                        const int px2 = hx * 7 + (cl >> 1);
                        const int cell = ((m * 2 + (kg >> 1)) * 256 +
                                          (rp + 1) * 16 + (px2 + 1)) * 8 + (kg & 1) * 4;
                        *(f16x4*)(Bbuf_hi + cell) = ph.v;
                        *(f16x4*)(Bbuf_lo + cell) = pl.v;
                    }
                }
            }
        }
    }
    __syncthreads();

    // Phase D: conv2 both half-passes into registers (no LDS writes yet).
    const int ocb = wave * 16;
    float bias[4];
    #pragma unroll
    for (int r = 0; r < 4; ++r) bias[r] = b2[ocb + kg * 4 + r];

    float pooled[7][4];
    conv2_half<0, 8>(w2t_hi, w2t_lo, Bbuf_hi, Bbuf_lo, ocb, cl, kg, bias, &pooled[0]);
    conv2_half<8, 6>(w2t_hi, w2t_lo, Bbuf_hi, Bbuf_lo, ocb, cl, kg, bias, &pooled[4]);
    __syncthreads();   // all Bbuf reads done -> F may alias base

    const bool wlane = ((cl & 1) == 0) && (cl < 14);
    const int px2 = cl >> 1;
    if (wlane) {
        #pragma unroll
        for (int p = 0; p < 7; ++p) {
            #pragma unroll
            for (int r = 0; r < 4; ++r) {
                float m = pooled[p][r];
                _Float16 mh = (_Float16)m;
                _Float16 ml = (_Float16)(m - (float)mh);
                int o = (ocb + kg * 4 + r) * 49 + p * 7 + px2;
                Fhi[o] = mh; Flo[o] = ml;
            }
        }
    }
    __syncthreads();

    // Coalesced dump: 1568 dwords per plane
    unsigned* gh = (unsigned*)(feat_hi + (size_t)n * 3136);
    unsigned* gl = (unsigned*)(feat_lo + (size_t)n * 3136);
    const unsigned* sh = (const unsigned*)Fhi;
    const unsigned* sl = (const unsigned*)Flo;
    for (int i = tid; i < 1568; i += 256) { gh[i] = sh[i]; gl[i] = sl[i]; }
}

// ---------------------------------------------------------------------------
// Kernel 2: fused FC (split-fp16 MFMA) + hyperbolic MLR head.
// 256 blocks x 512 threads (8 waves). Block = 16-image M-tile; 8 waves split K
// (k-steps 13/13/12x6 of 98), combine in LDS, then MLR on the LDS h-tile.
// ---------------------------------------------------------------------------
__global__ __launch_bounds__(512) void fc_mlr(
    const _Float16* __restrict__ feat_hi, const _Float16* __restrict__ feat_lo,
    const _Float16* __restrict__ fw_hi,   const _Float16* __restrict__ fw_lo,
    const float* __restrict__ fb,
    const float* __restrict__ hw,   // (10,32)
    const float* __restrict__ hb,   // (10,32)
    float* __restrict__ out)        // (N,10)
{
    __shared__ float part[8][64][9];   // padded: stride 9 -> conflict-free
    __shared__ float Ht[16][33];

    const int tid  = threadIdx.x;
    const int lane = tid & 63;
    const int wave = tid >> 6;         // 0..7
    const int kg = lane >> 4, cl = lane & 15;
    const int m0 = blockIdx.x * 16;

    const int start = (wave < 2) ? wave * 13 : 26 + (wave - 2) * 12;
    const int nstep = (wave < 2) ? 13 : 12;
    const size_t koff = (size_t)start * 32 + kg * 8;

    const _Float16* ah  = feat_hi + (size_t)(m0 + cl) * 3136 + koff;
    const _Float16* al  = feat_lo + (size_t)(m0 + cl) * 3136 + koff;
    const _Float16* b0h = fw_hi + (size_t)cl * 3136 + koff;
    const _Float16* b0l = fw_lo + (size_t)cl * 3136 + koff;
    const _Float16* b1h = fw_hi + (size_t)(16 + cl) * 3136 + koff;
    const _Float16* b1l = fw_lo + (size_t)(16 + cl) * 3136 + koff;

    f32x4 acc0 = {0.f, 0.f, 0.f, 0.f}, acc1 = {0.f, 0.f, 0.f, 0.f};
    for (int s = 0; s < nstep; ++s) {
        int k0 = s * 32;
        f16x8 vah = *(const f16x8*)(ah + k0);
        f16x8 val_ = *(const f16x8*)(al + k0);
        f16x8 v0h = *(const f16x8*)(b0h + k0);
        f16x8 v0l = *(const f16x8*)(b0l + k0);
        f16x8 v1h = *(const f16x8*)(b1h + k0);
        f16x8 v1l = *(const f16x8*)(b1l + k0);
        acc0 = __builtin_amdgcn_mfma_f32_16x16x32_f16(vah, v0h, acc0, 0, 0, 0);
        acc0 = __builtin_amdgcn_mfma_f32_16x16x32_f16(val_, v0h, acc0, 0, 0, 0);
        acc0 = __builtin_amdgcn_mfma_f32_16x16x32_f16(vah, v0l, acc0, 0, 0, 0);
        acc1 = __builtin_amdgcn_mfma_f32_16x16x32_f16(vah, v1h, acc1, 0, 0, 0);
        acc1 = __builtin_amdgcn_mfma_f32_16x16x32_f16(val_, v1h, acc1, 0, 0, 0);
        acc1 = __builtin_amdgcn_mfma_f32_16x16x32_f16(vah, v1l, acc1, 0, 0, 0);
    }
    #pragma unroll
    for (int r = 0; r < 4; ++r) {
        part[wave][lane][r]     = acc0[r];
        part[wave][lane][4 + r] = acc1[r];
    }
    __syncthreads();

    // Reduce 8 partials -> h tile in LDS. 512 values, 1 per thread.
    {
        int col = tid & 31, row = tid >> 5;             // row = image 0..15
        int l  = ((row >> 2) << 4) + (col & 15);
        int rr = ((col >= 16) ? 4 : 0) + (row & 3);
        float s = 0.f;
        #pragma unroll
        for (int w = 0; w < 8; ++w) s += part[w][l][rr];
        Ht[row][col] = s + fb[col];
    }
    __syncthreads();

    // MLR head: 160 outputs (16 images x 10 classes), fp32.
    if (tid < 160) {
        int im = tid / 10, k = tid - im * 10;
        const float* xr = &Ht[im][0];
        const float* wr = hw + k * 32;
        const float* br = hb + k * 32;
        float x2 = 0.f, b2s = 0.f, ww = 0.f, xb = 0.f, xw = 0.f, wb = 0.f;
        #pragma unroll
        for (int i = 0; i < 32; ++i) {
            float xi = xr[i], wi = wr[i], bi = br[i];
            x2 += xi * xi;  b2s += bi * bi;  ww += wi * wi;
            xb += xi * bi;  xw += xi * wi;   wb += wi * bi;
        }
        float w_norm = sqrtf(ww);
        float wnc = fmaxf(w_norm, 1e-12f);
        float inner = -xb;
        float a_num = 1.f + 2.f * inner + x2;
        float b_num = 1.f - b2s;
        float den = 1.f + 2.f * inner + x2 * b2s;
        float alpha = a_num / fmaxf(den, EPSV);
        float beta = b_num / den;                 // raw denom, as in source
        float mob2 = alpha * alpha * b2s + 2.f * alpha * beta * inner + beta * beta * x2;
        float sq = sqrtf(mob2);
        const float MAXN = (float)(1.0 - 1e-5);
        const float MAXN2 = (float)((1.0 - 1e-5) * (1.0 - 1e-5));
        float normalizer = (sq > MAXN) ? (MAXN / fmaxf(sq, EPSV)) : 1.f;
        float mob2c = (sq < MAXN) ? mob2 : MAXN2;
        float hyper = (alpha * (-wb) + beta * xw) / wnc;
        hyper *= normalizer;
        float asin_in = 2.f * hyper / fmaxf(1.f - mob2c, EPSV);
        float scaler = 2.f / fmaxf(1.f - b2s, EPSV);
        out[(size_t)m0 * 10 + tid] = scaler * w_norm * asinhf(asin_in);
    }
}

// ---------------------------------------------------------------------------
extern "C" void kernel_launch(void* const* d_in, const int* in_sizes, int n_in,
                              void* d_out, int out_size, void* d_ws, size_t ws_size,
                              hipStream_t stream) {
    const float* x   = (const float*)d_in[0];
    const float* w1  = (const float*)d_in[1];
    const float* b1  = (const float*)d_in[2];
    const float* w2  = (const float*)d_in[3];
    const float* b2  = (const float*)d_in[4];
    const float* fw  = (const float*)d_in[5];
    const float* fb  = (const float*)d_in[6];
    const float* hw  = (const float*)d_in[7];
    const float* hb  = (const float*)d_in[8];
    float* out = (float*)d_out;

    const int N = 4096;
    char* ws = (char*)d_ws;
    _Float16* feat_hi = (_Float16*)ws;                        // 25,690,112 B
    _Float16* feat_lo = (_Float16*)(ws + 25690112);           // 25,690,112 B
    _Float16* w2t_hi  = (_Float16*)(ws + 51380224);           //     36,864 B
    _Float16* w2t_lo  = (_Float16*)(ws + 51417088);           //     36,864 B
    _Float16* fw_hi   = (_Float16*)(ws + 51453952);           //    200,704 B
    _Float16* fw_lo   = (_Float16*)(ws + 51654656);           //    200,704 B
    _Float16* w1p_hi  = (_Float16*)(ws + 51855360);           //      2,048 B
    _Float16* w1p_lo  = (_Float16*)(ws + 51857408);           //      2,048 B (end 51,859,456)

    prep_weights<<<(18432 + 100352 + 1024 + 255) / 256, 256, 0, stream>>>(
        w1, b1, w2, fw, w2t_hi, w2t_lo, fw_hi, fw_lo, w1p_hi, w1p_lo);
    conv_fused<<<N, 256, 0, stream>>>(x, w1p_hi, w1p_lo, w2t_hi, w2t_lo, b2,
                                      feat_hi, feat_lo);
    fc_mlr<<<N / 16, 512, 0, stream>>>(feat_hi, feat_lo, fw_hi, fw_lo, fb, hw, hb, out);
}